// Round 5
// baseline (623.477 us; speedup 1.0000x reference)
//
#include <hip/hip_runtime.h>
#include <math.h>

#define B_ 2
#define P_ 16384
#define C_ 5
#define S_ 4096
#define KNN_ 8
#define L_ 64

typedef unsigned short u16;
typedef unsigned int u32;
typedef unsigned long long u64;

// ---- static scratch: fully rewritten every call before any read ----
__device__ int    g_idxk[B_ * KNN_ * S_];
__device__ float  g_partials[256 * 128];   // [tail_block][slot], wave-coalesced
__device__ float  g_mnmx[B_][5];           // mn0,mx0,mn1,mx1,amax^2
__device__ int    g_hist[B_ * 4097];       // bin starts after scan (+sentinel)
__device__ int    g_cursor[B_ * 4096];     // scatter cursors
__device__ int    g_binof[B_ * P_];        // bin of each point
__device__ float4 g_recA[B_ * P_];         // (v0, v1, xx2d, idx_bits)
__device__ float4 g_recB[B_ * P_];         // (v0, v1, v2, xx3)

__device__ __forceinline__ float bf2f(u16 u) {
  union { u32 i; float f; } c; c.i = ((u32)u) << 16; return c.f;
}
__device__ __forceinline__ u16 f2bf(float f) {
  union { float f; u32 i; } c; c.f = f;
  u32 r = c.i + 0x7fffu + ((c.i >> 16) & 1u);
  return (u16)(r >> 16);
}
__device__ __forceinline__ float ldany(const void* p, int i, int f32) {
  return f32 ? ((const float*)p)[i] : bf2f(((const u16*)p)[i]);
}

// ---- (d, idx) -> fixed-exponent positive double; order == (d desc, idx asc); unique ----
__device__ __forceinline__ double packkey(float d, int idx) {
  u32 bits = __float_as_uint(d);
  u32 key = bits ^ ((u32)(((int)bits) >> 31) | 0x80000000u);  // monotone u32 map of f32
  int hi = (int)(0x3FF00000u | (key >> 12));
  int lo = (int)((key << 20) | ((u32)(16383 - idx) << 6));
  return __hiloint2double(hi, lo);
}
__device__ __forceinline__ int keyidx(double w) {
  return 16383 - (int)(((u32)__double2loint(w) >> 6) & 16383u);
}
// inverse of the monotone map: recover the float d stored in a key
__device__ __forceinline__ float keyd(double w) {
  u32 hi = (u32)__double2hiint(w), lo = (u32)__double2loint(w);
  u32 key = (hi << 12) | (lo >> 20);
  u32 mask = (u32)(((int)key) >> 31);
  u32 bits = key ^ ((~mask) | 0x80000000u);
  return __uint_as_float(bits);
}

__device__ __forceinline__ int chk_bad(const void* p, int n, int tid) {
  int bad = 0;
  for (int i = tid; i < n; i += 256) {
    float f = bf2f(((const u16*)p)[i]);
    if (!(f == f) || fabsf(f) > 1024.0f) bad = 1;
  }
  return bad;
}

// ---------------- prep: min/max + |max| bound, zero histogram ----------------
__global__ __launch_bounds__(256) void k_prep(const void* __restrict__ xv) {
  __shared__ int sbad;
  __shared__ float sred[4][5];
  int tid = threadIdx.x, b = blockIdx.x;
  if (tid == 0) sbad = 0;
  __syncthreads();
  if (chk_bad(xv, 1024, tid)) atomicOr(&sbad, 1);
  __syncthreads();
  const int f32 = sbad;
  int base0 = b * C_ * P_, base1 = base0 + P_, base2 = base1 + P_;
  float mn0 = INFINITY, mx0 = -INFINITY, mn1 = INFINITY, mx1 = -INFINITY, am = 0.f;
  for (int p = tid; p < P_; p += 256) {
    float v0 = ldany(xv, base0 + p, f32);
    float v1 = ldany(xv, base1 + p, f32);
    float v2 = ldany(xv, base2 + p, f32);
    mn0 = fminf(mn0, v0); mx0 = fmaxf(mx0, v0);
    mn1 = fminf(mn1, v1); mx1 = fmaxf(mx1, v1);
    am = fmaxf(am, fabsf(v2));
  }
  for (int off = 32; off; off >>= 1) {
    mn0 = fminf(mn0, __shfl_down(mn0, off)); mx0 = fmaxf(mx0, __shfl_down(mx0, off));
    mn1 = fminf(mn1, __shfl_down(mn1, off)); mx1 = fmaxf(mx1, __shfl_down(mx1, off));
    am = fmaxf(am, __shfl_down(am, off));
  }
  int l = tid & 63, g = tid >> 6;
  if (l == 0) {
    sred[g][0] = mn0; sred[g][1] = mx0; sred[g][2] = mn1; sred[g][3] = mx1; sred[g][4] = am;
  }
  __syncthreads();
  if (tid == 0) {
    float a0 = fminf(fminf(sred[0][0], sred[1][0]), fminf(sred[2][0], sred[3][0]));
    float a1 = fmaxf(fmaxf(sred[0][1], sred[1][1]), fmaxf(sred[2][1], sred[3][1]));
    float a2 = fminf(fminf(sred[0][2], sred[1][2]), fminf(sred[2][2], sred[3][2]));
    float a3 = fmaxf(fmaxf(sred[0][3], sred[1][3]), fmaxf(sred[2][3], sred[3][3]));
    float a4 = fmaxf(fmaxf(sred[0][4], sred[1][4]), fmaxf(sred[2][4], sred[3][4]));
    float aa = fmaxf(fmaxf(fabsf(a0), fabsf(a1)), fmaxf(fmaxf(fabsf(a2), fabsf(a3)), a4));
    g_mnmx[b][0] = a0; g_mnmx[b][1] = a1; g_mnmx[b][2] = a2; g_mnmx[b][3] = a3;
    g_mnmx[b][4] = aa * aa;
  }
  for (int i2 = tid; i2 < 4097; i2 += 256) g_hist[b * 4097 + i2] = 0;
}

// ---------------- histogram + per-point bin ----------------
__global__ __launch_bounds__(256) void k_hist(const void* __restrict__ xv) {
  __shared__ int sbad;
  int tid = threadIdx.x, blk = blockIdx.x;
  if (tid == 0) sbad = 0;
  __syncthreads();
  if (chk_bad(xv, 1024, tid)) atomicOr(&sbad, 1);
  __syncthreads();
  const int f32 = sbad;
  int b = blk >> 4;
  int pb = (blk & 15) * 1024;
  int base0 = b * C_ * P_, base1 = base0 + P_;
  float mn0 = g_mnmx[b][0], mx0 = g_mnmx[b][1], mn1 = g_mnmx[b][2], mx1 = g_mnmx[b][3];
  float r0 = __fsub_rn(mx0, mn0), r1 = __fsub_rn(mx1, mn1);
  float inv0 = (r0 > 0.f) ? 64.0f / r0 : 0.f;
  float inv1 = (r1 > 0.f) ? 64.0f / r1 : 0.f;
  for (int q = 0; q < 4; ++q) {
    int i = pb + q * 256 + tid;
    float v0 = ldany(xv, base0 + i, f32);
    float v1 = ldany(xv, base1 + i, f32);
    int bx = (int)fminf(fmaxf((v0 - mn0) * inv0, 0.f), 63.f);
    int by = (int)fminf(fmaxf((v1 - mn1) * inv1, 0.f), 63.f);
    int bin = by * 64 + bx;
    g_binof[b * P_ + i] = bin;
    atomicAdd(&g_hist[b * 4097 + bin], 1);
  }
}

// ---------------- exclusive prefix over 4096 bins (per b) ----------------
__global__ __launch_bounds__(256) void k_scan() {
  __shared__ int part[256];
  int b = blockIdx.x, t = threadIdx.x;
  int loc[16]; int s0 = 0;
  for (int q = 0; q < 16; ++q) { loc[q] = g_hist[b * 4097 + t * 16 + q]; s0 += loc[q]; }
  part[t] = s0;
  __syncthreads();
  for (int d2 = 1; d2 < 256; d2 <<= 1) {
    int v = (t >= d2) ? part[t - d2] : 0;
    __syncthreads();
    part[t] += v;
    __syncthreads();
  }
  int run = (t == 0) ? 0 : part[t - 1];
  for (int q = 0; q < 16; ++q) {
    g_hist[b * 4097 + t * 16 + q] = run;
    g_cursor[b * 4096 + t * 16 + q] = run;
    run += loc[q];
  }
  if (t == 0) g_hist[b * 4097 + 4096] = P_;
}

// ---------------- scatter points into binned records ----------------
__global__ __launch_bounds__(256) void k_scatter(const void* __restrict__ xv) {
  __shared__ int sbad;
  int tid = threadIdx.x, blk = blockIdx.x;
  if (tid == 0) sbad = 0;
  __syncthreads();
  if (chk_bad(xv, 1024, tid)) atomicOr(&sbad, 1);
  __syncthreads();
  const int f32 = sbad;
  int b = blk >> 4;
  int pb = (blk & 15) * 1024;
  int base0 = b * C_ * P_, base1 = base0 + P_, base2 = base1 + P_;
  for (int q = 0; q < 4; ++q) {
    int i = pb + q * 256 + tid;
    float a0 = ldany(xv, base0 + i, f32);
    float a1 = ldany(xv, base1 + i, f32);
    float a2 = ldany(xv, base2 + i, f32);
    // EXACT expression trees matching the brute-force kernel's staging:
    float xx2d = __fadd_rn(__fmul_rn(a0, a0), __fmul_rn(a1, a1));
    float xx3  = __fadd_rn(__fadd_rn(__fmul_rn(a0, a0), __fmul_rn(a1, a1)), __fmul_rn(a2, a2));
    int bin = g_binof[b * P_ + i];
    int pos = atomicAdd(&g_cursor[b * 4096 + bin], 1);
    g_recA[(b << 14) + pos] = make_float4(a0, a1, xx2d, __int_as_float(i));
    g_recB[(b << 14) + pos] = make_float4(a0, a1, a2, xx3);
  }
}

// ---------------- binned exact kNN, LDS hist + occupancy bitmask ----------------
// 8 lanes per query (octet). Cooperative 3x3 core (records split across lanes),
// then rings R>=2 round-robin per lane; empty bins cost one LDS-mask test.
__global__ __launch_bounds__(256) void k_knn2(const void* __restrict__ xv) {
  __shared__ int shist[4097];
  __shared__ u64 smask[64];
  __shared__ int sbad;
  int tid = threadIdx.x;
  if (tid == 0) sbad = 0;
  __syncthreads();
  if (chk_bad(xv, 1024, tid)) atomicOr(&sbad, 1);
  __syncthreads();
  const int f32 = sbad;

  int blk = blockIdx.x;
  int b = blk >> 7;                          // 128 blocks per batch element
  for (int i2 = tid; i2 < 4097; i2 += 256) shist[i2] = g_hist[b * 4097 + i2];
  __syncthreads();
  if (tid < 64) {
    u64 m = 0ull;
    int rb = tid * 64;
    for (int x = 0; x < 64; ++x)
      if (shist[rb + x + 1] > shist[rb + x]) m |= (1ull << x);
    smask[tid] = m;
  }
  __syncthreads();

  int o = tid & 7;
  int oct = blk * 32 + (tid >> 3);           // 0..8191 (b consistent with blk>>7)
  int s = oct & (S_ - 1);
  int base0 = b * C_ * P_, base1 = base0 + P_, base2 = base1 + P_;

  float mn0 = g_mnmx[b][0], mx0 = g_mnmx[b][1], mn1 = g_mnmx[b][2], mx1 = g_mnmx[b][3];
  float margin = 2e-5f * g_mnmx[b][4];
  float r0 = __fsub_rn(mx0, mn0), r1 = __fsub_rn(mx1, mn1);
  float w0 = r0 * 0.015625f, w1 = r1 * 0.015625f;
  float wmin = fminf(w0, w1) * 0.999f;       // conservative slack vs fp rounding
  float inv0 = (r0 > 0.f) ? 64.0f / r0 : 0.f;
  float inv1 = (r1 > 0.f) ? 64.0f / r1 : 0.f;
  const float4* recA = g_recA + (b << 14);
  const float4* recB = g_recB + (b << 14);

  // ---- phase A: nearest (2D) to lattice node s ----
  float mm0 = (float)(s & (L_ - 1)) * 0.015625f;
  float mm1 = (float)(s >> 6) * 0.015625f;
  float ps0 = __fadd_rn(__fmul_rn(mm0, r0), mn0);
  float ps1 = __fadd_rn(__fmul_rn(mm1, r1), mn1);
  float xx2q = __fadd_rn(__fmul_rn(ps0, ps0), __fmul_rn(ps1, ps1));
  int bqx = (int)fminf(fmaxf((ps0 - mn0) * inv0, 0.f), 63.f);
  int bqy = (int)fminf(fmaxf((ps1 - mn1) * inv1, 0.f), 63.f);
  double best = -1.0;
  // cooperative 3x3 core (Chebyshev <= 1): lanes split records of each bin
#pragma unroll
  for (int dy = -1; dy <= 1; ++dy) {
#pragma unroll
    for (int dx = -1; dx <= 1; ++dx) {
      int X = bqx + dx, Y = bqy + dy;
      if ((unsigned)X > 63u || (unsigned)Y > 63u) continue;
      if (!((smask[Y] >> X) & 1ull)) continue;
      int bin = Y * 64 + X;
      int st = shist[bin], en = shist[bin + 1];
      for (int j2 = st + o; j2 < en; j2 += 8) {
        float4 rc = recA[j2];
        float dot = __fadd_rn(__fmul_rn(rc.x, ps0), __fmul_rn(rc.y, ps1));
        float inner = __fmul_rn(-2.0f, dot);
        float d = __fsub_rn(__fsub_rn(-rc.z, inner), xx2q);
        best = fmax(best, packkey(d, __float_as_int(rc.w)));
      }
    }
  }
  for (int R = 2; R < 64; ++R) {
    double bnd = best;
    bnd = fmax(bnd, __shfl_xor(bnd, 1, 8));
    bnd = fmax(bnd, __shfl_xor(bnd, 2, 8));
    bnd = fmax(bnd, __shfl_xor(bnd, 4, 8));
    if (bnd >= 1.0) {
      float lb = (float)(R - 1) * wmin;
      float ub = __fadd_rn(-(lb * lb), margin);   // max possible computed d in ring >= R
      if (ub < keyd(bnd)) break;
    }
    int cnt = 8 * R;
    for (int t = o; t < cnt; t += 8) {
      int X, Y;
      {
        int side = 2 * R + 1;
        if (t < side)          { X = bqx - R + t;          Y = bqy - R; }
        else if (t < 2 * side) { X = bqx - R + (t - side); Y = bqy + R; }
        else {
          int u = t - 2 * side, m2 = 2 * R - 1;
          if (u < m2) { X = bqx - R; Y = bqy - R + 1 + u; }
          else        { X = bqx + R; Y = bqy - R + 1 + (u - m2); }
        }
      }
      if ((unsigned)X > 63u || (unsigned)Y > 63u) continue;
      if (!((smask[Y] >> X) & 1ull)) continue;
      int bin = Y * 64 + X;
      int st = shist[bin], en = shist[bin + 1];
      for (int j2 = st; j2 < en; ++j2) {
        float4 rc = recA[j2];
        float dot = __fadd_rn(__fmul_rn(rc.x, ps0), __fmul_rn(rc.y, ps1));
        float inner = __fmul_rn(-2.0f, dot);
        float d = __fsub_rn(__fsub_rn(-rc.z, inner), xx2q);
        best = fmax(best, packkey(d, __float_as_int(rc.w)));
      }
    }
  }
  best = fmax(best, __shfl_xor(best, 1, 8));
  best = fmax(best, __shfl_xor(best, 2, 8));
  best = fmax(best, __shfl_xor(best, 4, 8));
  int qi = keyidx(best) & (P_ - 1);

  // ---- phase B: top-8 (3D) from point qi ----
  float q0 = ldany(xv, base0 + qi, f32);
  float q1 = ldany(xv, base1 + qi, f32);
  float q2 = ldany(xv, base2 + qi, f32);
  float xx3q = __fadd_rn(__fadd_rn(__fmul_rn(q0, q0), __fmul_rn(q1, q1)), __fmul_rn(q2, q2));
  int cx = (int)fminf(fmaxf((q0 - mn0) * inv0, 0.f), 63.f);
  int cy = (int)fminf(fmaxf((q1 - mn1) * inv1, 0.f), 63.f);
  double acc[8];
#pragma unroll
  for (int k = 0; k < 8; ++k) acc[k] = -1.0;
  // cooperative 3x3 core
#pragma unroll
  for (int dy = -1; dy <= 1; ++dy) {
#pragma unroll
    for (int dx = -1; dx <= 1; ++dx) {
      int X = cx + dx, Y = cy + dy;
      if ((unsigned)X > 63u || (unsigned)Y > 63u) continue;
      if (!((smask[Y] >> X) & 1ull)) continue;
      int bin = Y * 64 + X;
      int st = shist[bin], en = shist[bin + 1];
      for (int j2 = st + o; j2 < en; j2 += 8) {
        float4 rc = recB[j2];
        int idx = __float_as_int(((const float*)recA)[j2 * 4 + 3]);
        float dot = __fadd_rn(__fadd_rn(__fmul_rn(rc.x, q0), __fmul_rn(rc.y, q1)),
                              __fmul_rn(rc.z, q2));
        float inner = __fmul_rn(-2.0f, dot);
        float d = __fsub_rn(__fsub_rn(-rc.w, inner), xx3q);
        double key = packkey(d, idx);
        if (key > acc[7]) {
          double tmp = key;
#pragma unroll
          for (int k = 0; k < 8; ++k) {
            double hi2 = fmax(acc[k], tmp), lo2 = fmin(acc[k], tmp);
            acc[k] = hi2; tmp = lo2;
          }
        }
      }
    }
  }
  for (int R = 2; R < 64; ++R) {
    double bnd = acc[7];                     // union-8th >= max over lanes of lane-8th
    bnd = fmax(bnd, __shfl_xor(bnd, 1, 8));
    bnd = fmax(bnd, __shfl_xor(bnd, 2, 8));
    bnd = fmax(bnd, __shfl_xor(bnd, 4, 8));
    if (bnd >= 1.0) {
      float lb = (float)(R - 1) * wmin;      // 2D lower bound of 3D distance
      float ub = __fadd_rn(-(lb * lb), margin);
      if (ub < keyd(bnd)) break;
    }
    int cnt = 8 * R;
    for (int t = o; t < cnt; t += 8) {
      int X, Y;
      {
        int side = 2 * R + 1;
        if (t < side)          { X = cx - R + t;          Y = cy - R; }
        else if (t < 2 * side) { X = cx - R + (t - side); Y = cy + R; }
        else {
          int u = t - 2 * side, m2 = 2 * R - 1;
          if (u < m2) { X = cx - R; Y = cy - R + 1 + u; }
          else        { X = cx + R; Y = cy - R + 1 + (u - m2); }
        }
      }
      if ((unsigned)X > 63u || (unsigned)Y > 63u) continue;
      if (!((smask[Y] >> X) & 1ull)) continue;
      int bin = Y * 64 + X;
      int st = shist[bin], en = shist[bin + 1];
      for (int j2 = st; j2 < en; ++j2) {
        float4 rc = recB[j2];
        int idx = __float_as_int(((const float*)recA)[j2 * 4 + 3]);
        float dot = __fadd_rn(__fadd_rn(__fmul_rn(rc.x, q0), __fmul_rn(rc.y, q1)),
                              __fmul_rn(rc.z, q2));
        float inner = __fmul_rn(-2.0f, dot);
        float d = __fsub_rn(__fsub_rn(-rc.w, inner), xx3q);
        double key = packkey(d, idx);
        if (key > acc[7]) {
          double tmp = key;
#pragma unroll
          for (int k = 0; k < 8; ++k) {
            double hi2 = fmax(acc[k], tmp), lo2 = fmin(acc[k], tmp);
            acc[k] = hi2; tmp = lo2;
          }
        }
      }
    }
  }
  // 8 extraction rounds across the octet (keys unique -> exact)
  double wk = 0.0;
#pragma unroll
  for (int r2 = 0; r2 < 8; ++r2) {
    double w = acc[0];
    w = fmax(w, __shfl_xor(w, 1, 8));
    w = fmax(w, __shfl_xor(w, 2, 8));
    w = fmax(w, __shfl_xor(w, 4, 8));
    if (o == r2) wk = w;
    bool cns = (acc[0] == w);
#pragma unroll
    for (int k = 0; k < 7; ++k) acc[k] = cns ? acc[k + 1] : acc[k];
    acc[7] = cns ? -1.0 : acc[7];
  }
  g_idxk[b * 32768 + o * 4096 + s] = keyidx(wk);   // rank-major (B,k,s)
}

// ---------------- BN partial sums (decoupled tail) ----------------
__global__ __launch_bounds__(256) void k_tail(const void* __restrict__ x,
                                              const void* __restrict__ Wpos,
                                              const void* __restrict__ bpos,
                                              const void* __restrict__ Wconv,
                                              const void* __restrict__ bconv) {
  __shared__ float sWpos[320], sbpos[32], sWconv[128], sbconv[32];
  __shared__ float sacc[16][128];
  __shared__ int sbx, sbw;
  int tid = threadIdx.x;
  if (tid == 0) { sbx = 0; sbw = 0; }
  __syncthreads();
  if (chk_bad(x, 1024, tid)) atomicOr(&sbx, 1);
  if (chk_bad(Wpos, 320, tid) | chk_bad(Wconv, 128, tid)) atomicOr(&sbw, 1);
  __syncthreads();
  const int f32 = sbx, wf32 = sbw;

  int id = blockIdx.x * 256 + tid;          // element in [0, 65536)
  int b = id >> 15, n = id & 32767;
  const int* fb = g_idxk + b * 32768;
  int base0 = b * C_ * P_;
  int p = fb[n] & (P_ - 1);
  int p0 = fb[n & ~7] & (P_ - 1);
  float xvv[4], pc3[3];
#pragma unroll
  for (int cc = 0; cc < 4; ++cc) xvv[cc] = ldany(x, base0 + cc * P_ + p, f32);
#pragma unroll
  for (int cc = 0; cc < 3; ++cc) pc3[cc] = ldany(x, base0 + cc * P_ + p0, f32);

  for (int i2 = tid; i2 < 320; i2 += 256) sWpos[i2] = ldany(Wpos, i2, wf32);
  if (tid < 128) sWconv[tid] = ldany(Wconv, tid, wf32);
  if (tid < 32) { sbpos[tid] = ldany(bpos, tid, wf32); sbconv[tid] = ldany(bconv, tid, wf32); }
  __syncthreads();

  float d0 = xvv[0] - pc3[0], d1 = xvv[1] - pc3[1], d2 = xvv[2] - pc3[2];
  float sq = d0 * d0 + d1 * d1 + d2 * d2;
  float temp = (sq > 0.0f) ? sqrtf(sq) : 0.0f;
  float pe[10] = {xvv[0], xvv[1], xvv[2], pc3[0], pc3[1], pc3[2], d0, d1, d2, temp};
#pragma unroll
  for (int o = 0; o < 64; ++o) {
    float v;
    if (o < 32) {
      v = sbconv[o];
#pragma unroll
      for (int cc = 0; cc < 4; ++cc) v = fmaf(sWconv[o * 4 + cc], xvv[cc], v);
    } else {
      v = sbpos[o - 32];
#pragma unroll
      for (int cc = 0; cc < 10; ++cc) v = fmaf(sWpos[(o - 32) * 10 + cc], pe[cc], v);
    }
    float sv = v, qv = v * v;
    for (int m = 1; m < 16; m <<= 1) { sv += __shfl_xor(sv, m, 16); qv += __shfl_xor(qv, m, 16); }
    if ((tid & 15) == 0) { sacc[tid >> 4][o * 2] = sv; sacc[tid >> 4][o * 2 + 1] = qv; }
  }
  __syncthreads();
  if (tid < 128) {
    float a = 0.f;
#pragma unroll
    for (int w = 0; w < 16; ++w) a += sacc[w][tid];
    g_partials[blockIdx.x * 128 + tid] = a;
  }
}

// ---------------- pass 2 : BN stats + recompute + attention + output ----------------
__global__ __launch_bounds__(256) void k_pass2(const void* __restrict__ x,
                                               const void* __restrict__ Wpos,
                                               const void* __restrict__ bpos,
                                               const void* __restrict__ Wconv,
                                               const void* __restrict__ bconv,
                                               const void* __restrict__ g1,
                                               const void* __restrict__ be1,
                                               const void* __restrict__ g2,
                                               const void* __restrict__ be2,
                                               const void* __restrict__ Wa1,
                                               const void* __restrict__ ba1,
                                               const void* __restrict__ Wa2,
                                               const void* __restrict__ ba2,
                                               const void* __restrict__ Wb1,
                                               const void* __restrict__ bb1,
                                               const void* __restrict__ Wb2,
                                               const void* __restrict__ bb2,
                                               void* __restrict__ out) {
  __shared__ float sWpos[320], sbpos[32], sWconv[128], sbconv[32];
  __shared__ float sWa1[2048], sba1[32], sWa2[32];
  __shared__ float sWb1[64 * 65];
  __shared__ float sbb1[64], sWb2[256], sbb2[64], sstats[128];
  __shared__ float sp2[2][128];
  __shared__ float sba2;
  __shared__ int sbx, sbw;
  int tid = threadIdx.x;
  if (tid == 0) { sbx = 0; sbw = 0; }
  __syncthreads();
  if (chk_bad(x, 1024, tid)) atomicOr(&sbx, 1);
  if (chk_bad(Wa1, 2048, tid) | chk_bad(Wb1, 4096, tid)) atomicOr(&sbw, 1);
  __syncthreads();
  int xf32 = sbx, wf32 = sbw;

  int g = blockIdx.x * 32 + (tid >> 3);
  int j = tid & 7;
  int b = g >> 12, i = g & (S_ - 1);
  int n = i * 8 + j;
  const int* fb = g_idxk + b * 32768;
  int xbase = b * C_ * P_;
  int p = fb[n] & (P_ - 1);
  int p0 = fb[n & ~7] & (P_ - 1);
  float xvv[4];
#pragma unroll
  for (int c = 0; c < 4; ++c) xvv[c] = ldany(x, xbase + c * P_ + p, xf32);
  float pc3[3];
#pragma unroll
  for (int c = 0; c < 3; ++c) pc3[c] = ldany(x, xbase + c * P_ + p0, xf32);
  float xc0 = ldany(x, xbase + p0, xf32);
  float xc1 = ldany(x, xbase + P_ + p0, xf32);
  float xc2 = ldany(x, xbase + 2 * P_ + p0, xf32);
  float xc3 = ldany(x, xbase + 3 * P_ + p0, xf32);

  {
    int slot = tid & 127, half = tid >> 7;
    float a0 = 0.f, a1 = 0.f;
    for (int blk = half * 128; blk < half * 128 + 128; blk += 2) {
      a0 += g_partials[blk * 128 + slot];
      a1 += g_partials[(blk + 1) * 128 + slot];
    }
    sp2[half][slot] = a0 + a1;
  }
  for (int i2 = tid; i2 < 320; i2 += 256) sWpos[i2] = ldany(Wpos, i2, wf32);
  if (tid < 128) sWconv[tid] = ldany(Wconv, tid, wf32);
  if (tid < 32) { sbpos[tid] = ldany(bpos, tid, wf32); sbconv[tid] = ldany(bconv, tid, wf32); }
  for (int i2 = tid; i2 < 2048; i2 += 256) sWa1[i2] = ldany(Wa1, i2, wf32);
  for (int i2 = tid; i2 < 4096; i2 += 256) sWb1[(i2 >> 6) * 65 + (i2 & 63)] = ldany(Wb1, i2, wf32);
  if (tid >= 32 && tid < 64) { sba1[tid - 32] = ldany(ba1, tid - 32, wf32); sWa2[tid - 32] = ldany(Wa2, tid - 32, wf32); }
  if (tid >= 64 && tid < 128) { sbb1[tid - 64] = ldany(bb1, tid - 64, wf32); sbb2[tid - 64] = ldany(bb2, tid - 64, wf32); }
  sWb2[tid] = ldany(Wb2, tid, wf32);
  if (tid == 0) sba2 = ldany(ba2, 0, wf32);
  __syncthreads();
  if (tid >= 128 && tid < 192) {
    int ch = tid - 128;
    float sum = sp2[0][ch * 2] + sp2[1][ch * 2];
    float sq = sp2[0][ch * 2 + 1] + sp2[1][ch * 2 + 1];
    float mean = sum * (1.0f / 65536.0f);
    float var = sq * (1.0f / 65536.0f) - mean * mean;
    int o = ch & 31;
    float gg = ldany(ch < 32 ? g1 : g2, o, wf32);
    float be = ldany(ch < 32 ? be1 : be2, o, wf32);
    float scale = gg / sqrtf(var + 1e-5f);
    sstats[ch * 2] = scale;
    sstats[ch * 2 + 1] = be - mean * scale;
  }
  __syncthreads();

  float d0 = xvv[0] - pc3[0], d1 = xvv[1] - pc3[1], d2 = xvv[2] - pc3[2];
  float sq = d0 * d0 + d1 * d1 + d2 * d2;
  float temp = (sq > 0.0f) ? sqrtf(sq) : 0.0f;
  float pe[10] = {xvv[0], xvv[1], xvv[2], pc3[0], pc3[1], pc3[2], d0, d1, d2, temp};
  float feat[64];
#pragma unroll
  for (int o = 0; o < 32; ++o) {
    float acc = sbconv[o];
#pragma unroll
    for (int c = 0; c < 4; ++c) acc = fmaf(sWconv[o * 4 + c], xvv[c], acc);
    feat[o] = acc;
  }
#pragma unroll
  for (int o = 0; o < 32; ++o) {
    float acc = sbpos[o];
#pragma unroll
    for (int c = 0; c < 10; ++c) acc = fmaf(sWpos[o * 10 + c], pe[c], acc);
    feat[32 + o] = acc;
  }
#pragma unroll
  for (int c = 0; c < 64; ++c) {
    float v = fmaf(feat[c], sstats[c * 2], sstats[c * 2 + 1]);
    feat[c] = (v >= 0.f) ? v : 0.2f * v;
  }
  float att = sba2;
#pragma unroll 4
  for (int h = 0; h < 32; ++h) {
    float a0 = 0.f, a1 = 0.f, a2 = 0.f, a3 = 0.f;
#pragma unroll
    for (int c = 0; c < 64; c += 4) {
      a0 = fmaf(sWa1[h * 64 + c],     feat[c],     a0);
      a1 = fmaf(sWa1[h * 64 + c + 1], feat[c + 1], a1);
      a2 = fmaf(sWa1[h * 64 + c + 2], feat[c + 2], a2);
      a3 = fmaf(sWa1[h * 64 + c + 3], feat[c + 3], a3);
    }
    float acc = sba1[h] + ((a0 + a1) + (a2 + a3));
    acc = (acc >= 0.f) ? acc : 0.2f * acc;
    att = fmaf(sWa2[h], acc, att);
  }
  float mxv = att;
  for (int mk = 1; mk < 8; mk <<= 1) mxv = fmaxf(mxv, __shfl_xor(mxv, mk, 8));
  float e = expf(att - mxv);
  float se = e;
  for (int mk = 1; mk < 8; mk <<= 1) se += __shfl_xor(se, mk, 8);
  float a = e / se;
#pragma unroll
  for (int c = 0; c < 64; ++c) {
    float w = feat[c] * a;
    w += __shfl_xor(w, 1, 8);
    w += __shfl_xor(w, 2, 8);
    w += __shfl_xor(w, 4, 8);
    feat[c] = w;
  }
  int obase = b * 69 * S_;
#pragma unroll
  for (int oc = 0; oc < 8; ++oc) {
    int o = j * 8 + oc;
    float a0 = sbb1[o], a1 = 0.f, a2 = 0.f, a3 = 0.f;
#pragma unroll
    for (int c = 0; c < 64; c += 4) {
      a0 = fmaf(sWb1[o * 65 + c],     feat[c],     a0);
      a1 = fmaf(sWb1[o * 65 + c + 1], feat[c + 1], a1);
      a2 = fmaf(sWb1[o * 65 + c + 2], feat[c + 2], a2);
      a3 = fmaf(sWb1[o * 65 + c + 3], feat[c + 3], a3);
    }
    float acc = (a0 + a1) + (a2 + a3);
    float acc2 = sbb2[o];
    acc2 = fmaf(sWb2[o * 4 + 0], xc0, acc2);
    acc2 = fmaf(sWb2[o * 4 + 1], xc1, acc2);
    acc2 = fmaf(sWb2[o * 4 + 2], xc2, acc2);
    acc2 = fmaf(sWb2[o * 4 + 3], xc3, acc2);
    float r = acc + acc2;
    r = (r >= 0.f) ? r : 0.01f * r;
    int oi = obase + (5 + o) * S_ + i;
    if (xf32) ((float*)out)[oi] = r; else ((u16*)out)[oi] = f2bf(r);
  }
  if (j == 0) {
#pragma unroll
    for (int c = 0; c < 5; ++c) {
      int oi = obase + c * S_ + i;
      if (xf32) ((float*)out)[oi] = ((const float*)x)[xbase + c * P_ + p0];
      else      ((u16*)out)[oi]   = ((const u16*)x)[xbase + c * P_ + p0];
    }
  }
}

extern "C" void kernel_launch(void* const* d_in, const int* in_sizes, int n_in,
                              void* d_out, int out_size, void* d_ws, size_t ws_size,
                              hipStream_t stream) {
  const void* x     = d_in[0];
  const void* Wpos  = d_in[1];
  const void* bpos  = d_in[2];
  const void* g2    = d_in[3];
  const void* be2   = d_in[4];
  const void* Wconv = d_in[5];
  const void* bconv = d_in[6];
  const void* g1    = d_in[7];
  const void* be1   = d_in[8];
  const void* Wa1   = d_in[9];
  const void* ba1   = d_in[10];
  const void* Wa2   = d_in[11];
  const void* ba2   = d_in[12];
  const void* Wb1   = d_in[13];
  const void* bb1   = d_in[14];
  const void* Wb2   = d_in[15];
  const void* bb2   = d_in[16];
  (void)d_ws; (void)ws_size; (void)in_sizes; (void)n_in;

  hipLaunchKernelGGL(k_prep,    dim3(2),   dim3(256), 0, stream, x);
  hipLaunchKernelGGL(k_hist,    dim3(32),  dim3(256), 0, stream, x);
  hipLaunchKernelGGL(k_scan,    dim3(2),   dim3(256), 0, stream);
  hipLaunchKernelGGL(k_scatter, dim3(32),  dim3(256), 0, stream, x);
  hipLaunchKernelGGL(k_knn2,    dim3(256), dim3(256), 0, stream, x);
  hipLaunchKernelGGL(k_tail,    dim3(256), dim3(256), 0, stream, x,
                     Wpos, bpos, Wconv, bconv);
  hipLaunchKernelGGL(k_pass2,   dim3(256), dim3(256), 0, stream, x,
                     Wpos, bpos, Wconv, bconv, g1, be1, g2, be2,
                     Wa1, ba1, Wa2, ba2, Wb1, bb1, Wb2, bb2, d_out);
}

// Round 6
// 615.039 us; speedup vs baseline: 1.0137x; 1.0137x over previous
//
#include <hip/hip_runtime.h>
#include <math.h>

#define B_ 2
#define P_ 16384
#define C_ 5
#define S_ 4096
#define KNN_ 8
#define L_ 64

typedef unsigned short u16;
typedef unsigned int u32;
typedef unsigned long long u64;

// ---- static scratch: fully rewritten every call before any read ----
__device__ int    g_idxk[B_ * KNN_ * S_];
__device__ float  g_partials[256 * 128];   // [tail_block][slot], wave-coalesced
__device__ float  g_mnmx[B_][5];           // mn0,mx0,mn1,mx1,amax^2
__device__ int    g_hist[B_ * 4097];       // bin starts after scan (+sentinel)
__device__ int    g_cursor[B_ * 4096];     // scatter cursors
__device__ int    g_binof[B_ * P_];        // bin of each point
__device__ int    g_dt[B_ * 4096];         // Chebyshev dist to nearest occupied bin
__device__ float4 g_recA[B_ * P_];         // (v0, v1, xx2d, idx_bits)
__device__ float4 g_recB[B_ * P_];         // (v0, v1, v2, xx3)
__device__ u16    g_idxsc[B_ * P_];        // original idx per scattered record

__device__ __forceinline__ float bf2f(u16 u) {
  union { u32 i; float f; } c; c.i = ((u32)u) << 16; return c.f;
}
__device__ __forceinline__ u16 f2bf(float f) {
  union { float f; u32 i; } c; c.f = f;
  u32 r = c.i + 0x7fffu + ((c.i >> 16) & 1u);
  return (u16)(r >> 16);
}
__device__ __forceinline__ float ldany(const void* p, int i, int f32) {
  return f32 ? ((const float*)p)[i] : bf2f(((const u16*)p)[i]);
}

// ---- (d, idx) -> fixed-exponent positive double; order == (d desc, idx asc); unique ----
__device__ __forceinline__ double packkey(float d, int idx) {
  u32 bits = __float_as_uint(d);
  u32 key = bits ^ ((u32)(((int)bits) >> 31) | 0x80000000u);  // monotone u32 map of f32
  int hi = (int)(0x3FF00000u | (key >> 12));
  int lo = (int)((key << 20) | ((u32)(16383 - idx) << 6));
  return __hiloint2double(hi, lo);
}
__device__ __forceinline__ int keyidx(double w) {
  return 16383 - (int)(((u32)__double2loint(w) >> 6) & 16383u);
}
// inverse of the monotone map: recover the float d stored in a key
__device__ __forceinline__ float keyd(double w) {
  u32 hi = (u32)__double2hiint(w), lo = (u32)__double2loint(w);
  u32 key = (hi << 12) | (lo >> 20);
  u32 mask = (u32)(((int)key) >> 31);
  u32 bits = key ^ ((~mask) | 0x80000000u);
  return __uint_as_float(bits);
}

__device__ __forceinline__ int chk_bad(const void* p, int n, int tid) {
  int bad = 0;
  for (int i = tid; i < n; i += 256) {
    float f = bf2f(((const u16*)p)[i]);
    if (!(f == f) || fabsf(f) > 1024.0f) bad = 1;
  }
  return bad;
}

// named-register sorted-desc top-8 insert (no arrays -> no scratch risk)
#define INS8(key)                                                        \
  do {                                                                   \
    if ((key) > a7) {                                                    \
      double t_ = (key), h_;                                             \
      h_ = fmax(a0, t_); t_ = fmin(a0, t_); a0 = h_;                     \
      h_ = fmax(a1, t_); t_ = fmin(a1, t_); a1 = h_;                     \
      h_ = fmax(a2, t_); t_ = fmin(a2, t_); a2 = h_;                     \
      h_ = fmax(a3, t_); t_ = fmin(a3, t_); a3 = h_;                     \
      h_ = fmax(a4, t_); t_ = fmin(a4, t_); a4 = h_;                     \
      h_ = fmax(a5, t_); t_ = fmin(a5, t_); a5 = h_;                     \
      h_ = fmax(a6, t_); t_ = fmin(a6, t_); a6 = h_;                     \
      a7 = fmax(a7, t_);                                                 \
    }                                                                    \
  } while (0)

// ring cell enumeration (Chebyshev ring R, t-th cell of 8R)
__device__ __forceinline__ void ringcell(int R, int t, int cx, int cy, int& X, int& Y) {
  int side = 2 * R + 1;
  if (t < side)          { X = cx - R + t;          Y = cy - R; }
  else if (t < 2 * side) { X = cx - R + (t - side); Y = cy + R; }
  else {
    int u = t - 2 * side, m2 = 2 * R - 1;
    if (u < m2) { X = cx - R; Y = cy - R + 1 + u; }
    else        { X = cx + R; Y = cy - R + 1 + (u - m2); }
  }
}

// ---------------- prep: min/max + |max| bound, zero histogram ----------------
__global__ __launch_bounds__(256) void k_prep(const void* __restrict__ xv) {
  __shared__ int sbad;
  __shared__ float sred[4][5];
  int tid = threadIdx.x, b = blockIdx.x;
  if (tid == 0) sbad = 0;
  __syncthreads();
  if (chk_bad(xv, 1024, tid)) atomicOr(&sbad, 1);
  __syncthreads();
  const int f32 = sbad;
  int base0 = b * C_ * P_, base1 = base0 + P_, base2 = base1 + P_;
  float mn0 = INFINITY, mx0 = -INFINITY, mn1 = INFINITY, mx1 = -INFINITY, am = 0.f;
  for (int p = tid; p < P_; p += 256) {
    float v0 = ldany(xv, base0 + p, f32);
    float v1 = ldany(xv, base1 + p, f32);
    float v2 = ldany(xv, base2 + p, f32);
    mn0 = fminf(mn0, v0); mx0 = fmaxf(mx0, v0);
    mn1 = fminf(mn1, v1); mx1 = fmaxf(mx1, v1);
    am = fmaxf(am, fabsf(v2));
  }
  for (int off = 32; off; off >>= 1) {
    mn0 = fminf(mn0, __shfl_down(mn0, off)); mx0 = fmaxf(mx0, __shfl_down(mx0, off));
    mn1 = fminf(mn1, __shfl_down(mn1, off)); mx1 = fmaxf(mx1, __shfl_down(mx1, off));
    am = fmaxf(am, __shfl_down(am, off));
  }
  int l = tid & 63, g = tid >> 6;
  if (l == 0) {
    sred[g][0] = mn0; sred[g][1] = mx0; sred[g][2] = mn1; sred[g][3] = mx1; sred[g][4] = am;
  }
  __syncthreads();
  if (tid == 0) {
    float a0 = fminf(fminf(sred[0][0], sred[1][0]), fminf(sred[2][0], sred[3][0]));
    float a1 = fmaxf(fmaxf(sred[0][1], sred[1][1]), fmaxf(sred[2][1], sred[3][1]));
    float a2 = fminf(fminf(sred[0][2], sred[1][2]), fminf(sred[2][2], sred[3][2]));
    float a3 = fmaxf(fmaxf(sred[0][3], sred[1][3]), fmaxf(sred[2][3], sred[3][3]));
    float a4 = fmaxf(fmaxf(sred[0][4], sred[1][4]), fmaxf(sred[2][4], sred[3][4]));
    float aa = fmaxf(fmaxf(fabsf(a0), fabsf(a1)), fmaxf(fmaxf(fabsf(a2), fabsf(a3)), a4));
    g_mnmx[b][0] = a0; g_mnmx[b][1] = a1; g_mnmx[b][2] = a2; g_mnmx[b][3] = a3;
    g_mnmx[b][4] = aa * aa;
  }
  for (int i2 = tid; i2 < 4097; i2 += 256) g_hist[b * 4097 + i2] = 0;
}

// ---------------- histogram + per-point bin ----------------
__global__ __launch_bounds__(256) void k_hist(const void* __restrict__ xv) {
  __shared__ int sbad;
  int tid = threadIdx.x, blk = blockIdx.x;
  if (tid == 0) sbad = 0;
  __syncthreads();
  if (chk_bad(xv, 1024, tid)) atomicOr(&sbad, 1);
  __syncthreads();
  const int f32 = sbad;
  int b = blk >> 4;
  int pb = (blk & 15) * 1024;
  int base0 = b * C_ * P_, base1 = base0 + P_;
  float mn0 = g_mnmx[b][0], mx0 = g_mnmx[b][1], mn1 = g_mnmx[b][2], mx1 = g_mnmx[b][3];
  float r0 = __fsub_rn(mx0, mn0), r1 = __fsub_rn(mx1, mn1);
  float inv0 = (r0 > 0.f) ? 64.0f / r0 : 0.f;
  float inv1 = (r1 > 0.f) ? 64.0f / r1 : 0.f;
  for (int q = 0; q < 4; ++q) {
    int i = pb + q * 256 + tid;
    float v0 = ldany(xv, base0 + i, f32);
    float v1 = ldany(xv, base1 + i, f32);
    int bx = (int)fminf(fmaxf((v0 - mn0) * inv0, 0.f), 63.f);
    int by = (int)fminf(fmaxf((v1 - mn1) * inv1, 0.f), 63.f);
    int bin = by * 64 + bx;
    g_binof[b * P_ + i] = bin;
    atomicAdd(&g_hist[b * 4097 + bin], 1);
  }
}

// ---------------- exclusive prefix over 4096 bins (per b) ----------------
__global__ __launch_bounds__(256) void k_scan() {
  __shared__ int part[256];
  int b = blockIdx.x, t = threadIdx.x;
  int loc[16]; int s0 = 0;
  for (int q = 0; q < 16; ++q) { loc[q] = g_hist[b * 4097 + t * 16 + q]; s0 += loc[q]; }
  part[t] = s0;
  __syncthreads();
  for (int d2 = 1; d2 < 256; d2 <<= 1) {
    int v = (t >= d2) ? part[t - d2] : 0;
    __syncthreads();
    part[t] += v;
    __syncthreads();
  }
  int run = (t == 0) ? 0 : part[t - 1];
  for (int q = 0; q < 16; ++q) {
    g_hist[b * 4097 + t * 16 + q] = run;
    g_cursor[b * 4096 + t * 16 + q] = run;
    run += loc[q];
  }
  if (t == 0) g_hist[b * 4097 + 4096] = P_;
}

// ---------------- scatter points into binned records ----------------
__global__ __launch_bounds__(256) void k_scatter(const void* __restrict__ xv) {
  __shared__ int sbad;
  int tid = threadIdx.x, blk = blockIdx.x;
  if (tid == 0) sbad = 0;
  __syncthreads();
  if (chk_bad(xv, 1024, tid)) atomicOr(&sbad, 1);
  __syncthreads();
  const int f32 = sbad;
  int b = blk >> 4;
  int pb = (blk & 15) * 1024;
  int base0 = b * C_ * P_, base1 = base0 + P_, base2 = base1 + P_;
  for (int q = 0; q < 4; ++q) {
    int i = pb + q * 256 + tid;
    float a0 = ldany(xv, base0 + i, f32);
    float a1 = ldany(xv, base1 + i, f32);
    float a2 = ldany(xv, base2 + i, f32);
    // EXACT expression trees matching the verified brute-force staging:
    float xx2d = __fadd_rn(__fmul_rn(a0, a0), __fmul_rn(a1, a1));
    float xx3  = __fadd_rn(__fadd_rn(__fmul_rn(a0, a0), __fmul_rn(a1, a1)), __fmul_rn(a2, a2));
    int bin = g_binof[b * P_ + i];
    int pos = atomicAdd(&g_cursor[b * 4096 + bin], 1);
    g_recA[(b << 14) + pos] = make_float4(a0, a1, xx2d, __int_as_float(i));
    g_recB[(b << 14) + pos] = make_float4(a0, a1, a2, xx3);
    g_idxsc[(b << 14) + pos] = (u16)i;
  }
}

// ---------------- Chebyshev distance transform to nearest occupied bin ----------------
// 2 blocks x 256 thr. rowdist via bit scans, then column fold with early break.
__global__ __launch_bounds__(256) void k_dt() {
  __shared__ u64 occm[64];
  __shared__ short rowd[64][64];
  int b = blockIdx.x, t = threadIdx.x;
  if (t < 64) {
    u64 m = 0ull;
    const int* h = g_hist + b * 4097 + t * 64;
    for (int x = 0; x < 64; ++x)
      if (h[x + 1] > h[x]) m |= (1ull << x);
    occm[t] = m;
  }
  __syncthreads();
#pragma unroll
  for (int q = 0; q < 16; ++q) {            // rowdist for 16 cells per thread
    int c = q * 256 + t, y = c >> 6, x = c & 63;
    u64 m = occm[y];
    int rd = 127;
    if (m) {
      u64 hi = m >> x;
      int dhi = hi ? (__ffsll((long long)hi) - 1) : 127;
      u64 lo = (x < 63) ? (m & (((u64)1 << (x + 1)) - 1)) : m;
      int dlo = lo ? (x - (63 - __clzll((long long)lo))) : 127;
      rd = min(dhi, dlo);
    }
    rowd[y][x] = (short)rd;
  }
  __syncthreads();
#pragma unroll
  for (int q = 0; q < 16; ++q) {            // column fold: dt = min_y' max(|dy|, rowd)
    int c = q * 256 + t, y = c >> 6, x = c & 63;
    int best = 127;
    for (int dy = 0; dy < 64; ++dy) {
      if (dy >= best) break;
      int y1 = y - dy, y2 = y + dy;
      if (y1 >= 0) { int v = rowd[y1][x]; best = min(best, (dy > v) ? dy : v); }
      if (dy && y2 < 64) { int v = rowd[y2][x]; best = min(best, (dy > v) ? dy : v); }
    }
    g_dt[(b << 12) + c] = best;
  }
}

// ---------------- binned exact kNN with dt-accelerated ring start ----------------
__global__ __launch_bounds__(256) void k_knn2(const void* __restrict__ xv) {
  __shared__ int shist[4097];
  __shared__ u64 smask[64];
  __shared__ int sbad;
  int tid = threadIdx.x;
  if (tid == 0) sbad = 0;
  __syncthreads();
  if (chk_bad(xv, 1024, tid)) atomicOr(&sbad, 1);
  __syncthreads();
  const int f32 = sbad;

  int blk = blockIdx.x;
  int b = blk >> 7;                          // 128 blocks per batch element
  for (int i2 = tid; i2 < 4097; i2 += 256) shist[i2] = g_hist[b * 4097 + i2];
  __syncthreads();
  if (tid < 64) {
    u64 m = 0ull;
    int rb = tid * 64;
    for (int x = 0; x < 64; ++x)
      if (shist[rb + x + 1] > shist[rb + x]) m |= (1ull << x);
    smask[tid] = m;
  }
  __syncthreads();

  int o = tid & 7;
  int oct = blk * 32 + (tid >> 3);           // 0..8191
  int s = oct & (S_ - 1);
  int base0 = b * C_ * P_, base1 = base0 + P_, base2 = base1 + P_;

  float mn0 = g_mnmx[b][0], mx0 = g_mnmx[b][1], mn1 = g_mnmx[b][2], mx1 = g_mnmx[b][3];
  float margin = 2e-5f * g_mnmx[b][4];
  float r0 = __fsub_rn(mx0, mn0), r1 = __fsub_rn(mx1, mn1);
  float w0 = r0 * 0.015625f, w1 = r1 * 0.015625f;
  float wmin = fminf(w0, w1) * 0.999f;       // conservative slack vs fp rounding
  const float4* recA = g_recA + (b << 14);
  const float4* recB = g_recB + (b << 14);

  // ---- phase A: nearest (2D) to lattice node s (node = corner of bin (s&63, s>>6)) ----
  float mm0 = (float)(s & (L_ - 1)) * 0.015625f;
  float mm1 = (float)(s >> 6) * 0.015625f;
  float ps0 = __fadd_rn(__fmul_rn(mm0, r0), mn0);
  float ps1 = __fadd_rn(__fmul_rn(mm1, r1), mn1);
  float xx2q = __fadd_rn(__fmul_rn(ps0, ps0), __fmul_rn(ps1, ps1));
  int bqx = s & 63, bqy = s >> 6;            // exact bin identity, no fp refloor
  int R0 = g_dt[(b << 12) + s];              // rings < R0 provably empty
  double bestA = -1.0;
  if (R0 <= 1) {                             // cooperative 3x3 core, records split by o
#pragma unroll
    for (int dy = -1; dy <= 1; ++dy) {
#pragma unroll
      for (int dx = -1; dx <= 1; ++dx) {
        int X = bqx + dx, Y = bqy + dy;
        if ((unsigned)X > 63u || (unsigned)Y > 63u) continue;
        if (!((smask[Y] >> X) & 1ull)) continue;
        int bin = Y * 64 + X;
        int st = shist[bin], en = shist[bin + 1];
        for (int j2 = st + o; j2 < en; j2 += 8) {
          float4 rc = recA[j2];
          float dot = __fadd_rn(__fmul_rn(rc.x, ps0), __fmul_rn(rc.y, ps1));
          float inner = __fmul_rn(-2.0f, dot);
          float d = __fsub_rn(__fsub_rn(-rc.z, inner), xx2q);
          bestA = fmax(bestA, packkey(d, __float_as_int(rc.w)));
        }
      }
    }
  }
  for (int R = (R0 < 2 ? 2 : R0); R < 64; ++R) {
    double bnd = bestA;
    bnd = fmax(bnd, __shfl_xor(bnd, 1, 8));
    bnd = fmax(bnd, __shfl_xor(bnd, 2, 8));
    bnd = fmax(bnd, __shfl_xor(bnd, 4, 8));
    if (bnd >= 1.0) {
      float lb = (float)(R - 1) * wmin;
      float ub = __fadd_rn(-(lb * lb), margin);
      if (ub < keyd(bnd)) break;
    }
    int cnt = 8 * R;
    for (int t = o; t < cnt; t += 8) {
      int X, Y;
      ringcell(R, t, bqx, bqy, X, Y);
      if ((unsigned)X > 63u || (unsigned)Y > 63u) continue;
      if (!((smask[Y] >> X) & 1ull)) continue;
      int bin = Y * 64 + X;
      int st = shist[bin], en = shist[bin + 1];
      for (int j2 = st; j2 < en; ++j2) {
        float4 rc = recA[j2];
        float dot = __fadd_rn(__fmul_rn(rc.x, ps0), __fmul_rn(rc.y, ps1));
        float inner = __fmul_rn(-2.0f, dot);
        float d = __fsub_rn(__fsub_rn(-rc.z, inner), xx2q);
        bestA = fmax(bestA, packkey(d, __float_as_int(rc.w)));
      }
    }
  }
  bestA = fmax(bestA, __shfl_xor(bestA, 1, 8));
  bestA = fmax(bestA, __shfl_xor(bestA, 2, 8));
  bestA = fmax(bestA, __shfl_xor(bestA, 4, 8));
  int qi = keyidx(bestA) & (P_ - 1);

  // ---- phase B: top-8 (3D) from data point qi (its bin is occupied; dt=0) ----
  float q0 = ldany(xv, base0 + qi, f32);
  float q1 = ldany(xv, base1 + qi, f32);
  float q2 = ldany(xv, base2 + qi, f32);
  float xx3q = __fadd_rn(__fadd_rn(__fmul_rn(q0, q0), __fmul_rn(q1, q1)), __fmul_rn(q2, q2));
  int qbin = g_binof[b * P_ + qi];           // bin identity consistent with scatter
  int cx = qbin & 63, cy = qbin >> 6;
  double a0 = -1.0, a1 = -1.0, a2 = -1.0, a3 = -1.0,
         a4 = -1.0, a5 = -1.0, a6 = -1.0, a7 = -1.0;
  // cooperative 3x3 core
#pragma unroll
  for (int dy = -1; dy <= 1; ++dy) {
#pragma unroll
    for (int dx = -1; dx <= 1; ++dx) {
      int X = cx + dx, Y = cy + dy;
      if ((unsigned)X > 63u || (unsigned)Y > 63u) continue;
      if (!((smask[Y] >> X) & 1ull)) continue;
      int bin = Y * 64 + X;
      int st = shist[bin], en = shist[bin + 1];
      for (int j2 = st + o; j2 < en; j2 += 8) {
        float4 rc = recB[j2];
        int idx = (int)g_idxsc[(b << 14) + j2];
        float dot = __fadd_rn(__fadd_rn(__fmul_rn(rc.x, q0), __fmul_rn(rc.y, q1)),
                              __fmul_rn(rc.z, q2));
        float inner = __fmul_rn(-2.0f, dot);
        float d = __fsub_rn(__fsub_rn(-rc.w, inner), xx3q);
        double key = packkey(d, idx);
        INS8(key);
      }
    }
  }
  for (int R = 2; R < 64; ++R) {
    double bnd = a7;                         // union-8th >= max over lanes of lane-8th
    bnd = fmax(bnd, __shfl_xor(bnd, 1, 8));
    bnd = fmax(bnd, __shfl_xor(bnd, 2, 8));
    bnd = fmax(bnd, __shfl_xor(bnd, 4, 8));
    if (bnd >= 1.0) {
      float lb = (float)(R - 1) * wmin;      // 2D lower bound of 3D distance
      float ub = __fadd_rn(-(lb * lb), margin);
      if (ub < keyd(bnd)) break;
    }
    int cnt = 8 * R;
    for (int t = o; t < cnt; t += 8) {
      int X, Y;
      ringcell(R, t, cx, cy, X, Y);
      if ((unsigned)X > 63u || (unsigned)Y > 63u) continue;
      if (!((smask[Y] >> X) & 1ull)) continue;
      int bin = Y * 64 + X;
      int st = shist[bin], en = shist[bin + 1];
      for (int j2 = st; j2 < en; ++j2) {
        float4 rc = recB[j2];
        int idx = (int)g_idxsc[(b << 14) + j2];
        float dot = __fadd_rn(__fadd_rn(__fmul_rn(rc.x, q0), __fmul_rn(rc.y, q1)),
                              __fmul_rn(rc.z, q2));
        float inner = __fmul_rn(-2.0f, dot);
        float d = __fsub_rn(__fsub_rn(-rc.w, inner), xx3q);
        double key = packkey(d, idx);
        INS8(key);
      }
    }
  }
  // 8 extraction rounds across the octet (keys unique -> exact)
  double wk = 0.0;
#pragma unroll
  for (int r2 = 0; r2 < 8; ++r2) {
    double w = a0;
    w = fmax(w, __shfl_xor(w, 1, 8));
    w = fmax(w, __shfl_xor(w, 2, 8));
    w = fmax(w, __shfl_xor(w, 4, 8));
    if (o == r2) wk = w;
    bool cns = (a0 == w);
    a0 = cns ? a1 : a0; a1 = cns ? a2 : a1; a2 = cns ? a3 : a2; a3 = cns ? a4 : a3;
    a4 = cns ? a5 : a4; a5 = cns ? a6 : a5; a6 = cns ? a7 : a6; a7 = cns ? -1.0 : a7;
  }
  g_idxk[b * 32768 + o * 4096 + s] = keyidx(wk);   // rank-major (B,k,s)
}

// ---------------- BN partial sums (decoupled tail) ----------------
__global__ __launch_bounds__(256) void k_tail(const void* __restrict__ x,
                                              const void* __restrict__ Wpos,
                                              const void* __restrict__ bpos,
                                              const void* __restrict__ Wconv,
                                              const void* __restrict__ bconv) {
  __shared__ float sWpos[320], sbpos[32], sWconv[128], sbconv[32];
  __shared__ float sacc[16][128];
  __shared__ int sbx, sbw;
  int tid = threadIdx.x;
  if (tid == 0) { sbx = 0; sbw = 0; }
  __syncthreads();
  if (chk_bad(x, 1024, tid)) atomicOr(&sbx, 1);
  if (chk_bad(Wpos, 320, tid) | chk_bad(Wconv, 128, tid)) atomicOr(&sbw, 1);
  __syncthreads();
  const int f32 = sbx, wf32 = sbw;

  int id = blockIdx.x * 256 + tid;          // element in [0, 65536)
  int b = id >> 15, n = id & 32767;
  const int* fb = g_idxk + b * 32768;
  int base0 = b * C_ * P_;
  int p = fb[n] & (P_ - 1);
  int p0 = fb[n & ~7] & (P_ - 1);
  float xvv[4], pc3[3];
#pragma unroll
  for (int cc = 0; cc < 4; ++cc) xvv[cc] = ldany(x, base0 + cc * P_ + p, f32);
#pragma unroll
  for (int cc = 0; cc < 3; ++cc) pc3[cc] = ldany(x, base0 + cc * P_ + p0, f32);

  for (int i2 = tid; i2 < 320; i2 += 256) sWpos[i2] = ldany(Wpos, i2, wf32);
  if (tid < 128) sWconv[tid] = ldany(Wconv, tid, wf32);
  if (tid < 32) { sbpos[tid] = ldany(bpos, tid, wf32); sbconv[tid] = ldany(bconv, tid, wf32); }
  __syncthreads();

  float d0 = xvv[0] - pc3[0], d1 = xvv[1] - pc3[1], d2 = xvv[2] - pc3[2];
  float sq = d0 * d0 + d1 * d1 + d2 * d2;
  float temp = (sq > 0.0f) ? sqrtf(sq) : 0.0f;
  float pe[10] = {xvv[0], xvv[1], xvv[2], pc3[0], pc3[1], pc3[2], d0, d1, d2, temp};
#pragma unroll
  for (int o = 0; o < 64; ++o) {
    float v;
    if (o < 32) {
      v = sbconv[o];
#pragma unroll
      for (int cc = 0; cc < 4; ++cc) v = fmaf(sWconv[o * 4 + cc], xvv[cc], v);
    } else {
      v = sbpos[o - 32];
#pragma unroll
      for (int cc = 0; cc < 10; ++cc) v = fmaf(sWpos[(o - 32) * 10 + cc], pe[cc], v);
    }
    float sv = v, qv = v * v;
    for (int m = 1; m < 16; m <<= 1) { sv += __shfl_xor(sv, m, 16); qv += __shfl_xor(qv, m, 16); }
    if ((tid & 15) == 0) { sacc[tid >> 4][o * 2] = sv; sacc[tid >> 4][o * 2 + 1] = qv; }
  }
  __syncthreads();
  if (tid < 128) {
    float a = 0.f;
#pragma unroll
    for (int w = 0; w < 16; ++w) a += sacc[w][tid];
    g_partials[blockIdx.x * 128 + tid] = a;
  }
}

// ---------------- pass 2 : BN stats + recompute + attention + output ----------------
__global__ __launch_bounds__(256) void k_pass2(const void* __restrict__ x,
                                               const void* __restrict__ Wpos,
                                               const void* __restrict__ bpos,
                                               const void* __restrict__ Wconv,
                                               const void* __restrict__ bconv,
                                               const void* __restrict__ g1,
                                               const void* __restrict__ be1,
                                               const void* __restrict__ g2,
                                               const void* __restrict__ be2,
                                               const void* __restrict__ Wa1,
                                               const void* __restrict__ ba1,
                                               const void* __restrict__ Wa2,
                                               const void* __restrict__ ba2,
                                               const void* __restrict__ Wb1,
                                               const void* __restrict__ bb1,
                                               const void* __restrict__ Wb2,
                                               const void* __restrict__ bb2,
                                               void* __restrict__ out) {
  __shared__ float sWpos[320], sbpos[32], sWconv[128], sbconv[32];
  __shared__ float sWa1[2048], sba1[32], sWa2[32];
  __shared__ float sWb1[64 * 65];
  __shared__ float sbb1[64], sWb2[256], sbb2[64], sstats[128];
  __shared__ float sp2[2][128];
  __shared__ float sba2;
  __shared__ int sbx, sbw;
  int tid = threadIdx.x;
  if (tid == 0) { sbx = 0; sbw = 0; }
  __syncthreads();
  if (chk_bad(x, 1024, tid)) atomicOr(&sbx, 1);
  if (chk_bad(Wa1, 2048, tid) | chk_bad(Wb1, 4096, tid)) atomicOr(&sbw, 1);
  __syncthreads();
  int xf32 = sbx, wf32 = sbw;

  int g = blockIdx.x * 32 + (tid >> 3);
  int j = tid & 7;
  int b = g >> 12, i = g & (S_ - 1);
  int n = i * 8 + j;
  const int* fb = g_idxk + b * 32768;
  int xbase = b * C_ * P_;
  int p = fb[n] & (P_ - 1);
  int p0 = fb[n & ~7] & (P_ - 1);
  float xvv[4];
#pragma unroll
  for (int c = 0; c < 4; ++c) xvv[c] = ldany(x, xbase + c * P_ + p, xf32);
  float pc3[3];
#pragma unroll
  for (int c = 0; c < 3; ++c) pc3[c] = ldany(x, xbase + c * P_ + p0, xf32);
  float xc0 = ldany(x, xbase + p0, xf32);
  float xc1 = ldany(x, xbase + P_ + p0, xf32);
  float xc2 = ldany(x, xbase + 2 * P_ + p0, xf32);
  float xc3 = ldany(x, xbase + 3 * P_ + p0, xf32);

  {
    int slot = tid & 127, half = tid >> 7;
    float a0 = 0.f, a1 = 0.f;
    for (int blk = half * 128; blk < half * 128 + 128; blk += 2) {
      a0 += g_partials[blk * 128 + slot];
      a1 += g_partials[(blk + 1) * 128 + slot];
    }
    sp2[half][slot] = a0 + a1;
  }
  for (int i2 = tid; i2 < 320; i2 += 256) sWpos[i2] = ldany(Wpos, i2, wf32);
  if (tid < 128) sWconv[tid] = ldany(Wconv, tid, wf32);
  if (tid < 32) { sbpos[tid] = ldany(bpos, tid, wf32); sbconv[tid] = ldany(bconv, tid, wf32); }
  for (int i2 = tid; i2 < 2048; i2 += 256) sWa1[i2] = ldany(Wa1, i2, wf32);
  for (int i2 = tid; i2 < 4096; i2 += 256) sWb1[(i2 >> 6) * 65 + (i2 & 63)] = ldany(Wb1, i2, wf32);
  if (tid >= 32 && tid < 64) { sba1[tid - 32] = ldany(ba1, tid - 32, wf32); sWa2[tid - 32] = ldany(Wa2, tid - 32, wf32); }
  if (tid >= 64 && tid < 128) { sbb1[tid - 64] = ldany(bb1, tid - 64, wf32); sbb2[tid - 64] = ldany(bb2, tid - 64, wf32); }
  sWb2[tid] = ldany(Wb2, tid, wf32);
  if (tid == 0) sba2 = ldany(ba2, 0, wf32);
  __syncthreads();
  if (tid >= 128 && tid < 192) {
    int ch = tid - 128;
    float sum = sp2[0][ch * 2] + sp2[1][ch * 2];
    float sq = sp2[0][ch * 2 + 1] + sp2[1][ch * 2 + 1];
    float mean = sum * (1.0f / 65536.0f);
    float var = sq * (1.0f / 65536.0f) - mean * mean;
    int o = ch & 31;
    float gg = ldany(ch < 32 ? g1 : g2, o, wf32);
    float be = ldany(ch < 32 ? be1 : be2, o, wf32);
    float scale = gg / sqrtf(var + 1e-5f);
    sstats[ch * 2] = scale;
    sstats[ch * 2 + 1] = be - mean * scale;
  }
  __syncthreads();

  float d0 = xvv[0] - pc3[0], d1 = xvv[1] - pc3[1], d2 = xvv[2] - pc3[2];
  float sq = d0 * d0 + d1 * d1 + d2 * d2;
  float temp = (sq > 0.0f) ? sqrtf(sq) : 0.0f;
  float pe[10] = {xvv[0], xvv[1], xvv[2], pc3[0], pc3[1], pc3[2], d0, d1, d2, temp};
  float feat[64];
#pragma unroll
  for (int o = 0; o < 32; ++o) {
    float acc = sbconv[o];
#pragma unroll
    for (int c = 0; c < 4; ++c) acc = fmaf(sWconv[o * 4 + c], xvv[c], acc);
    feat[o] = acc;
  }
#pragma unroll
  for (int o = 0; o < 32; ++o) {
    float acc = sbpos[o];
#pragma unroll
    for (int c = 0; c < 10; ++c) acc = fmaf(sWpos[o * 10 + c], pe[c], acc);
    feat[32 + o] = acc;
  }
#pragma unroll
  for (int c = 0; c < 64; ++c) {
    float v = fmaf(feat[c], sstats[c * 2], sstats[c * 2 + 1]);
    feat[c] = (v >= 0.f) ? v : 0.2f * v;
  }
  float att = sba2;
#pragma unroll 4
  for (int h = 0; h < 32; ++h) {
    float a0 = 0.f, a1 = 0.f, a2 = 0.f, a3 = 0.f;
#pragma unroll
    for (int c = 0; c < 64; c += 4) {
      a0 = fmaf(sWa1[h * 64 + c],     feat[c],     a0);
      a1 = fmaf(sWa1[h * 64 + c + 1], feat[c + 1], a1);
      a2 = fmaf(sWa1[h * 64 + c + 2], feat[c + 2], a2);
      a3 = fmaf(sWa1[h * 64 + c + 3], feat[c + 3], a3);
    }
    float acc = sba1[h] + ((a0 + a1) + (a2 + a3));
    acc = (acc >= 0.f) ? acc : 0.2f * acc;
    att = fmaf(sWa2[h], acc, att);
  }
  float mxv = att;
  for (int mk = 1; mk < 8; mk <<= 1) mxv = fmaxf(mxv, __shfl_xor(mxv, mk, 8));
  float e = expf(att - mxv);
  float se = e;
  for (int mk = 1; mk < 8; mk <<= 1) se += __shfl_xor(se, mk, 8);
  float a = e / se;
#pragma unroll
  for (int c = 0; c < 64; ++c) {
    float w = feat[c] * a;
    w += __shfl_xor(w, 1, 8);
    w += __shfl_xor(w, 2, 8);
    w += __shfl_xor(w, 4, 8);
    feat[c] = w;
  }
  int obase = b * 69 * S_;
#pragma unroll
  for (int oc = 0; oc < 8; ++oc) {
    int o = j * 8 + oc;
    float a0 = sbb1[o], a1 = 0.f, a2 = 0.f, a3 = 0.f;
#pragma unroll
    for (int c = 0; c < 64; c += 4) {
      a0 = fmaf(sWb1[o * 65 + c],     feat[c],     a0);
      a1 = fmaf(sWb1[o * 65 + c + 1], feat[c + 1], a1);
      a2 = fmaf(sWb1[o * 65 + c + 2], feat[c + 2], a2);
      a3 = fmaf(sWb1[o * 65 + c + 3], feat[c + 3], a3);
    }
    float acc = (a0 + a1) + (a2 + a3);
    float acc2 = sbb2[o];
    acc2 = fmaf(sWb2[o * 4 + 0], xc0, acc2);
    acc2 = fmaf(sWb2[o * 4 + 1], xc1, acc2);
    acc2 = fmaf(sWb2[o * 4 + 2], xc2, acc2);
    acc2 = fmaf(sWb2[o * 4 + 3], xc3, acc2);
    float r = acc + acc2;
    r = (r >= 0.f) ? r : 0.01f * r;
    int oi = obase + (5 + o) * S_ + i;
    if (xf32) ((float*)out)[oi] = r; else ((u16*)out)[oi] = f2bf(r);
  }
  if (j == 0) {
#pragma unroll
    for (int c = 0; c < 5; ++c) {
      int oi = obase + c * S_ + i;
      if (xf32) ((float*)out)[oi] = ((const float*)x)[xbase + c * P_ + p0];
      else      ((u16*)out)[oi]   = ((const u16*)x)[xbase + c * P_ + p0];
    }
  }
}

extern "C" void kernel_launch(void* const* d_in, const int* in_sizes, int n_in,
                              void* d_out, int out_size, void* d_ws, size_t ws_size,
                              hipStream_t stream) {
  const void* x     = d_in[0];
  const void* Wpos  = d_in[1];
  const void* bpos  = d_in[2];
  const void* g2    = d_in[3];
  const void* be2   = d_in[4];
  const void* Wconv = d_in[5];
  const void* bconv = d_in[6];
  const void* g1    = d_in[7];
  const void* be1   = d_in[8];
  const void* Wa1   = d_in[9];
  const void* ba1   = d_in[10];
  const void* Wa2   = d_in[11];
  const void* ba2   = d_in[12];
  const void* Wb1   = d_in[13];
  const void* bb1   = d_in[14];
  const void* Wb2   = d_in[15];
  const void* bb2   = d_in[16];
  (void)d_ws; (void)ws_size; (void)in_sizes; (void)n_in;

  hipLaunchKernelGGL(k_prep,    dim3(2),   dim3(256), 0, stream, x);
  hipLaunchKernelGGL(k_hist,    dim3(32),  dim3(256), 0, stream, x);
  hipLaunchKernelGGL(k_scan,    dim3(2),   dim3(256), 0, stream);
  hipLaunchKernelGGL(k_scatter, dim3(32),  dim3(256), 0, stream, x);
  hipLaunchKernelGGL(k_dt,      dim3(2),   dim3(256), 0, stream);
  hipLaunchKernelGGL(k_knn2,    dim3(256), dim3(256), 0, stream, x);
  hipLaunchKernelGGL(k_tail,    dim3(256), dim3(256), 0, stream, x,
                     Wpos, bpos, Wconv, bconv);
  hipLaunchKernelGGL(k_pass2,   dim3(256), dim3(256), 0, stream, x,
                     Wpos, bpos, Wconv, bconv, g1, be1, g2, be2,
                     Wa1, ba1, Wa2, ba2, Wb1, bb1, Wb2, bb2, d_out);
}

// Round 7
// 369.146 us; speedup vs baseline: 1.6890x; 1.6661x over previous
//
#include <hip/hip_runtime.h>
#include <math.h>

#define B_ 2
#define P_ 16384
#define C_ 5
#define S_ 4096
#define KNN_ 8
#define L_ 64

typedef unsigned short u16;
typedef unsigned int u32;
typedef unsigned long long u64;

// ---- static scratch: fully rewritten every call before any read ----
__device__ int    g_idxk[B_ * KNN_ * S_];
__device__ float  g_partials[256 * 128];   // [tail_block][slot], wave-coalesced
__device__ float  g_mnmx[B_][5];           // mn0,mx0,mn1,mx1,amax^2
__device__ int    g_hist[B_ * 4097];       // bin starts after scan (+sentinel)
__device__ int    g_cursor[B_ * 4096];     // scatter cursors
__device__ int    g_binof[B_ * P_];        // bin of each point
__device__ int    g_dt[B_ * 4096];         // Chebyshev dist to nearest occupied bin
__device__ float4 g_recA[B_ * P_];         // (v0, v1, xx2d, idx_bits)
__device__ float4 g_recB[B_ * P_];         // (v0, v1, v2, xx3)
__device__ u16    g_idxsc[B_ * P_];        // original idx per scattered record

__device__ __forceinline__ float bf2f(u16 u) {
  union { u32 i; float f; } c; c.i = ((u32)u) << 16; return c.f;
}
__device__ __forceinline__ u16 f2bf(float f) {
  union { float f; u32 i; } c; c.f = f;
  u32 r = c.i + 0x7fffu + ((c.i >> 16) & 1u);
  return (u16)(r >> 16);
}
__device__ __forceinline__ float ldany(const void* p, int i, int f32) {
  return f32 ? ((const float*)p)[i] : bf2f(((const u16*)p)[i]);
}

// ---- (d, idx) -> fixed-exponent positive double; order == (d desc, idx asc); unique ----
__device__ __forceinline__ double packkey(float d, int idx) {
  u32 bits = __float_as_uint(d);
  u32 key = bits ^ ((u32)(((int)bits) >> 31) | 0x80000000u);  // monotone u32 map of f32
  int hi = (int)(0x3FF00000u | (key >> 12));
  int lo = (int)((key << 20) | ((u32)(16383 - idx) << 6));
  return __hiloint2double(hi, lo);
}
__device__ __forceinline__ int keyidx(double w) {
  return 16383 - (int)(((u32)__double2loint(w) >> 6) & 16383u);
}
// inverse of the monotone map: recover the float d stored in a key
__device__ __forceinline__ float keyd(double w) {
  u32 hi = (u32)__double2hiint(w), lo = (u32)__double2loint(w);
  u32 key = (hi << 12) | (lo >> 20);
  u32 mask = (u32)(((int)key) >> 31);
  u32 bits = key ^ ((~mask) | 0x80000000u);
  return __uint_as_float(bits);
}

__device__ __forceinline__ int chk_bad(const void* p, int n, int tid) {
  int bad = 0;
  for (int i = tid; i < n; i += 256) {
    float f = bf2f(((const u16*)p)[i]);
    if (!(f == f) || fabsf(f) > 1024.0f) bad = 1;
  }
  return bad;
}

// named-register sorted-desc top-8 insert
#define INS8(key)                                                        \
  do {                                                                   \
    if ((key) > a7) {                                                    \
      double t_ = (key), h_;                                             \
      h_ = fmax(a0, t_); t_ = fmin(a0, t_); a0 = h_;                     \
      h_ = fmax(a1, t_); t_ = fmin(a1, t_); a1 = h_;                     \
      h_ = fmax(a2, t_); t_ = fmin(a2, t_); a2 = h_;                     \
      h_ = fmax(a3, t_); t_ = fmin(a3, t_); a3 = h_;                     \
      h_ = fmax(a4, t_); t_ = fmin(a4, t_); a4 = h_;                     \
      h_ = fmax(a5, t_); t_ = fmin(a5, t_); a5 = h_;                     \
      h_ = fmax(a6, t_); t_ = fmin(a6, t_); a6 = h_;                     \
      a7 = fmax(a7, t_);                                                 \
    }                                                                    \
  } while (0)

#define MAX64(w)                                                         \
  do {                                                                   \
    w = fmax(w, __shfl_xor(w, 1, 64));                                   \
    w = fmax(w, __shfl_xor(w, 2, 64));                                   \
    w = fmax(w, __shfl_xor(w, 4, 64));                                   \
    w = fmax(w, __shfl_xor(w, 8, 64));                                   \
    w = fmax(w, __shfl_xor(w, 16, 64));                                  \
    w = fmax(w, __shfl_xor(w, 32, 64));                                  \
  } while (0)

// ring cell enumeration (Chebyshev ring R, t-th cell of 8R)
__device__ __forceinline__ void ringcell(int R, int t, int cx, int cy, int& X, int& Y) {
  int side = 2 * R + 1;
  if (t < side)          { X = cx - R + t;          Y = cy - R; }
  else if (t < 2 * side) { X = cx - R + (t - side); Y = cy + R; }
  else {
    int u = t - 2 * side, m2 = 2 * R - 1;
    if (u < m2) { X = cx - R; Y = cy - R + 1 + u; }
    else        { X = cx + R; Y = cy - R + 1 + (u - m2); }
  }
}

// ---------------- prep: min/max + |max| bound, zero histogram ----------------
__global__ __launch_bounds__(256) void k_prep(const void* __restrict__ xv) {
  __shared__ int sbad;
  __shared__ float sred[4][5];
  int tid = threadIdx.x, b = blockIdx.x;
  if (tid == 0) sbad = 0;
  __syncthreads();
  if (chk_bad(xv, 1024, tid)) atomicOr(&sbad, 1);
  __syncthreads();
  const int f32 = sbad;
  int base0 = b * C_ * P_, base1 = base0 + P_, base2 = base1 + P_;
  float mn0 = INFINITY, mx0 = -INFINITY, mn1 = INFINITY, mx1 = -INFINITY, am = 0.f;
  for (int p = tid; p < P_; p += 256) {
    float v0 = ldany(xv, base0 + p, f32);
    float v1 = ldany(xv, base1 + p, f32);
    float v2 = ldany(xv, base2 + p, f32);
    mn0 = fminf(mn0, v0); mx0 = fmaxf(mx0, v0);
    mn1 = fminf(mn1, v1); mx1 = fmaxf(mx1, v1);
    am = fmaxf(am, fabsf(v2));
  }
  for (int off = 32; off; off >>= 1) {
    mn0 = fminf(mn0, __shfl_down(mn0, off)); mx0 = fmaxf(mx0, __shfl_down(mx0, off));
    mn1 = fminf(mn1, __shfl_down(mn1, off)); mx1 = fmaxf(mx1, __shfl_down(mx1, off));
    am = fmaxf(am, __shfl_down(am, off));
  }
  int l = tid & 63, g = tid >> 6;
  if (l == 0) {
    sred[g][0] = mn0; sred[g][1] = mx0; sred[g][2] = mn1; sred[g][3] = mx1; sred[g][4] = am;
  }
  __syncthreads();
  if (tid == 0) {
    float a0 = fminf(fminf(sred[0][0], sred[1][0]), fminf(sred[2][0], sred[3][0]));
    float a1 = fmaxf(fmaxf(sred[0][1], sred[1][1]), fmaxf(sred[2][1], sred[3][1]));
    float a2 = fminf(fminf(sred[0][2], sred[1][2]), fminf(sred[2][2], sred[3][2]));
    float a3 = fmaxf(fmaxf(sred[0][3], sred[1][3]), fmaxf(sred[2][3], sred[3][3]));
    float a4 = fmaxf(fmaxf(sred[0][4], sred[1][4]), fmaxf(sred[2][4], sred[3][4]));
    float aa = fmaxf(fmaxf(fabsf(a0), fabsf(a1)), fmaxf(fmaxf(fabsf(a2), fabsf(a3)), a4));
    g_mnmx[b][0] = a0; g_mnmx[b][1] = a1; g_mnmx[b][2] = a2; g_mnmx[b][3] = a3;
    g_mnmx[b][4] = aa * aa;
  }
  for (int i2 = tid; i2 < 4097; i2 += 256) g_hist[b * 4097 + i2] = 0;
}

// ---------------- histogram + per-point bin ----------------
__global__ __launch_bounds__(256) void k_hist(const void* __restrict__ xv) {
  __shared__ int sbad;
  int tid = threadIdx.x, blk = blockIdx.x;
  if (tid == 0) sbad = 0;
  __syncthreads();
  if (chk_bad(xv, 1024, tid)) atomicOr(&sbad, 1);
  __syncthreads();
  const int f32 = sbad;
  int b = blk >> 4;
  int pb = (blk & 15) * 1024;
  int base0 = b * C_ * P_, base1 = base0 + P_;
  float mn0 = g_mnmx[b][0], mx0 = g_mnmx[b][1], mn1 = g_mnmx[b][2], mx1 = g_mnmx[b][3];
  float r0 = __fsub_rn(mx0, mn0), r1 = __fsub_rn(mx1, mn1);
  float inv0 = (r0 > 0.f) ? 64.0f / r0 : 0.f;
  float inv1 = (r1 > 0.f) ? 64.0f / r1 : 0.f;
  for (int q = 0; q < 4; ++q) {
    int i = pb + q * 256 + tid;
    float v0 = ldany(xv, base0 + i, f32);
    float v1 = ldany(xv, base1 + i, f32);
    int bx = (int)fminf(fmaxf((v0 - mn0) * inv0, 0.f), 63.f);
    int by = (int)fminf(fmaxf((v1 - mn1) * inv1, 0.f), 63.f);
    int bin = by * 64 + bx;
    g_binof[b * P_ + i] = bin;
    atomicAdd(&g_hist[b * 4097 + bin], 1);
  }
}

// ---------------- exclusive prefix over 4096 bins (per b) ----------------
__global__ __launch_bounds__(256) void k_scan() {
  __shared__ int part[256];
  int b = blockIdx.x, t = threadIdx.x;
  int loc[16]; int s0 = 0;
  for (int q = 0; q < 16; ++q) { loc[q] = g_hist[b * 4097 + t * 16 + q]; s0 += loc[q]; }
  part[t] = s0;
  __syncthreads();
  for (int d2 = 1; d2 < 256; d2 <<= 1) {
    int v = (t >= d2) ? part[t - d2] : 0;
    __syncthreads();
    part[t] += v;
    __syncthreads();
  }
  int run = (t == 0) ? 0 : part[t - 1];
  for (int q = 0; q < 16; ++q) {
    g_hist[b * 4097 + t * 16 + q] = run;
    g_cursor[b * 4096 + t * 16 + q] = run;
    run += loc[q];
  }
  if (t == 0) g_hist[b * 4097 + 4096] = P_;
}

// ---------------- scatter points into binned records ----------------
__global__ __launch_bounds__(256) void k_scatter(const void* __restrict__ xv) {
  __shared__ int sbad;
  int tid = threadIdx.x, blk = blockIdx.x;
  if (tid == 0) sbad = 0;
  __syncthreads();
  if (chk_bad(xv, 1024, tid)) atomicOr(&sbad, 1);
  __syncthreads();
  const int f32 = sbad;
  int b = blk >> 4;
  int pb = (blk & 15) * 1024;
  int base0 = b * C_ * P_, base1 = base0 + P_, base2 = base1 + P_;
  for (int q = 0; q < 4; ++q) {
    int i = pb + q * 256 + tid;
    float a0 = ldany(xv, base0 + i, f32);
    float a1 = ldany(xv, base1 + i, f32);
    float a2 = ldany(xv, base2 + i, f32);
    // EXACT expression trees matching the verified brute-force staging:
    float xx2d = __fadd_rn(__fmul_rn(a0, a0), __fmul_rn(a1, a1));
    float xx3  = __fadd_rn(__fadd_rn(__fmul_rn(a0, a0), __fmul_rn(a1, a1)), __fmul_rn(a2, a2));
    int bin = g_binof[b * P_ + i];
    int pos = atomicAdd(&g_cursor[b * 4096 + bin], 1);
    g_recA[(b << 14) + pos] = make_float4(a0, a1, xx2d, __int_as_float(i));
    g_recB[(b << 14) + pos] = make_float4(a0, a1, a2, xx3);
    g_idxsc[(b << 14) + pos] = (u16)i;
  }
}

// ---------------- Chebyshev distance transform to nearest occupied bin ----------------
__global__ __launch_bounds__(256) void k_dt() {
  __shared__ u64 occm[64];
  __shared__ short rowd[64][64];
  int b = blockIdx.x, t = threadIdx.x;
  if (t < 64) {
    u64 m = 0ull;
    const int* h = g_hist + b * 4097 + t * 64;
    for (int x = 0; x < 64; ++x)
      if (h[x + 1] > h[x]) m |= (1ull << x);
    occm[t] = m;
  }
  __syncthreads();
#pragma unroll
  for (int q = 0; q < 16; ++q) {            // rowdist for 16 cells per thread
    int c = q * 256 + t, y = c >> 6, x = c & 63;
    u64 m = occm[y];
    int rd = 127;
    if (m) {
      u64 hi = m >> x;
      int dhi = hi ? (__ffsll((long long)hi) - 1) : 127;
      u64 lo = (x < 63) ? (m & (((u64)1 << (x + 1)) - 1)) : m;
      int dlo = lo ? (x - (63 - __clzll((long long)lo))) : 127;
      rd = min(dhi, dlo);
    }
    rowd[y][x] = (short)rd;
  }
  __syncthreads();
#pragma unroll
  for (int q = 0; q < 16; ++q) {            // column fold: dt = min_y' max(|dy|, rowd)
    int c = q * 256 + t, y = c >> 6, x = c & 63;
    int best = 127;
    for (int dy = 0; dy < 64; ++dy) {
      if (dy >= best) break;
      int y1 = y - dy, y2 = y + dy;
      if (y1 >= 0) { int v = rowd[y1][x]; best = min(best, (dy > v) ? dy : v); }
      if (dy && y2 < 64) { int v = rowd[y2][x]; best = min(best, (dy > v) ? dy : v); }
    }
    g_dt[(b << 12) + c] = best;
  }
}

// ---------------- binned exact kNN: ONE 64-LANE WAVE PER QUERY ----------------
// Core bins: records split across all 64 lanes (coalesced float4).
// Rings R>=2: 8 groups x 8 lanes; groups take ring cells round-robin,
// lanes within a group split records stride 8.
__global__ __launch_bounds__(256, 4) void k_knn2(const void* __restrict__ xv) {
  __shared__ int shist[4097];
  __shared__ u64 smask[64];
  __shared__ int sbad;
  int tid = threadIdx.x;
  if (tid == 0) sbad = 0;
  __syncthreads();
  if (chk_bad(xv, 1024, tid)) atomicOr(&sbad, 1);
  __syncthreads();
  const int f32 = sbad;

  int blk = blockIdx.x;
  int b = blk >> 10;                         // 1024 blocks per batch element
  for (int i2 = tid; i2 < 4097; i2 += 256) shist[i2] = g_hist[b * 4097 + i2];
  __syncthreads();
  if (tid < 64) {
    u64 m = 0ull;
    int rb = tid * 64;
    for (int x = 0; x < 64; ++x)
      if (shist[rb + x + 1] > shist[rb + x]) m |= (1ull << x);
    smask[tid] = m;
  }
  __syncthreads();

  int l = tid & 63;                          // lane within the query's wave
  int grp = l >> 3, lo = l & 7;
  int q = blk * 4 + (tid >> 6);              // query id 0..8191 (b == q>>12)
  int s = q & (S_ - 1);
  int base0 = b * C_ * P_, base1 = base0 + P_, base2 = base1 + P_;

  float mn0 = g_mnmx[b][0], mx0 = g_mnmx[b][1], mn1 = g_mnmx[b][2], mx1 = g_mnmx[b][3];
  float margin = 2e-5f * g_mnmx[b][4];
  float r0 = __fsub_rn(mx0, mn0), r1 = __fsub_rn(mx1, mn1);
  float w0 = r0 * 0.015625f, w1 = r1 * 0.015625f;
  float wmin = fminf(w0, w1) * 0.999f;       // conservative slack vs fp rounding
  const float4* recA = g_recA + (b << 14);
  const float4* recB = g_recB + (b << 14);

  // ---- phase A: nearest (2D) to lattice node s ----
  float mm0 = (float)(s & (L_ - 1)) * 0.015625f;
  float mm1 = (float)(s >> 6) * 0.015625f;
  float ps0 = __fadd_rn(__fmul_rn(mm0, r0), mn0);
  float ps1 = __fadd_rn(__fmul_rn(mm1, r1), mn1);
  float xx2q = __fadd_rn(__fmul_rn(ps0, ps0), __fmul_rn(ps1, ps1));
  int bqx = s & 63, bqy = s >> 6;            // exact bin identity
  int R0 = g_dt[(b << 12) + s];              // rings < R0 provably empty
  double bestA = -1.0;
  if (R0 <= 1) {                             // 3x3 core: all 64 lanes split records
#pragma unroll
    for (int dy = -1; dy <= 1; ++dy) {
#pragma unroll
      for (int dx = -1; dx <= 1; ++dx) {
        int X = bqx + dx, Y = bqy + dy;
        if ((unsigned)X > 63u || (unsigned)Y > 63u) continue;
        if (!((smask[Y] >> X) & 1ull)) continue;
        int bin = Y * 64 + X;
        int st = shist[bin], en = shist[bin + 1];
        for (int j2 = st + l; j2 < en; j2 += 64) {
          float4 rc = recA[j2];
          float dot = __fadd_rn(__fmul_rn(rc.x, ps0), __fmul_rn(rc.y, ps1));
          float inner = __fmul_rn(-2.0f, dot);
          float d = __fsub_rn(__fsub_rn(-rc.z, inner), xx2q);
          bestA = fmax(bestA, packkey(d, __float_as_int(rc.w)));
        }
      }
    }
  }
  for (int R = (R0 < 2 ? 2 : R0); R < 64; ++R) {
    double bnd = bestA;
    MAX64(bnd);                              // exact union best
    if (bnd >= 1.0) {
      float lb = (float)(R - 1) * wmin;
      float ub = __fadd_rn(-(lb * lb), margin);
      if (ub < keyd(bnd)) break;
    }
    int cnt = 8 * R;
    for (int t = grp; t < cnt; t += 8) {
      int X, Y;
      ringcell(R, t, bqx, bqy, X, Y);
      if ((unsigned)X > 63u || (unsigned)Y > 63u) continue;
      if (!((smask[Y] >> X) & 1ull)) continue;
      int bin = Y * 64 + X;
      int st = shist[bin], en = shist[bin + 1];
      for (int j2 = st + lo; j2 < en; j2 += 8) {
        float4 rc = recA[j2];
        float dot = __fadd_rn(__fmul_rn(rc.x, ps0), __fmul_rn(rc.y, ps1));
        float inner = __fmul_rn(-2.0f, dot);
        float d = __fsub_rn(__fsub_rn(-rc.z, inner), xx2q);
        bestA = fmax(bestA, packkey(d, __float_as_int(rc.w)));
      }
    }
  }
  MAX64(bestA);
  int qi = keyidx(bestA) & (P_ - 1);

  // ---- phase B: top-8 (3D) from data point qi (its bin occupied) ----
  float q0 = ldany(xv, base0 + qi, f32);
  float q1 = ldany(xv, base1 + qi, f32);
  float q2 = ldany(xv, base2 + qi, f32);
  float xx3q = __fadd_rn(__fadd_rn(__fmul_rn(q0, q0), __fmul_rn(q1, q1)), __fmul_rn(q2, q2));
  int qbin = g_binof[b * P_ + qi];
  int cx = qbin & 63, cy = qbin >> 6;
  double a0 = -1.0, a1 = -1.0, a2 = -1.0, a3 = -1.0,
         a4 = -1.0, a5 = -1.0, a6 = -1.0, a7 = -1.0;
#pragma unroll
  for (int dy = -1; dy <= 1; ++dy) {         // 3x3 core: 64-lane record split
#pragma unroll
    for (int dx = -1; dx <= 1; ++dx) {
      int X = cx + dx, Y = cy + dy;
      if ((unsigned)X > 63u || (unsigned)Y > 63u) continue;
      if (!((smask[Y] >> X) & 1ull)) continue;
      int bin = Y * 64 + X;
      int st = shist[bin], en = shist[bin + 1];
      for (int j2 = st + l; j2 < en; j2 += 64) {
        float4 rc = recB[j2];
        int idx = (int)g_idxsc[(b << 14) + j2];
        float dot = __fadd_rn(__fadd_rn(__fmul_rn(rc.x, q0), __fmul_rn(rc.y, q1)),
                              __fmul_rn(rc.z, q2));
        float inner = __fmul_rn(-2.0f, dot);
        float d = __fsub_rn(__fsub_rn(-rc.w, inner), xx3q);
        double key = packkey(d, idx);
        INS8(key);
      }
    }
  }
  for (int R = 2; R < 64; ++R) {
    // exact union 8th-best across the wave (non-destructive extraction)
    double c0 = a0, c1 = a1, c2 = a2, c3 = a3, c4 = a4, c5 = a5, c6 = a6, c7 = a7;
    double w8 = -1.0;
#pragma unroll
    for (int r2 = 0; r2 < 8; ++r2) {
      double w = c0;
      MAX64(w);
      w8 = w;
      bool cns = (c0 == w);
      c0 = cns ? c1 : c0; c1 = cns ? c2 : c1; c2 = cns ? c3 : c2; c3 = cns ? c4 : c3;
      c4 = cns ? c5 : c4; c5 = cns ? c6 : c5; c6 = cns ? c7 : c6; c7 = cns ? -1.0 : c7;
    }
    if (w8 >= 1.0) {
      float lb = (float)(R - 1) * wmin;      // 2D lower bound of 3D distance
      float ub = __fadd_rn(-(lb * lb), margin);
      if (ub < keyd(w8)) break;
    }
    int cnt = 8 * R;
    for (int t = grp; t < cnt; t += 8) {
      int X, Y;
      ringcell(R, t, cx, cy, X, Y);
      if ((unsigned)X > 63u || (unsigned)Y > 63u) continue;
      if (!((smask[Y] >> X) & 1ull)) continue;
      int bin = Y * 64 + X;
      int st = shist[bin], en = shist[bin + 1];
      for (int j2 = st + lo; j2 < en; j2 += 8) {
        float4 rc = recB[j2];
        int idx = (int)g_idxsc[(b << 14) + j2];
        float dot = __fadd_rn(__fadd_rn(__fmul_rn(rc.x, q0), __fmul_rn(rc.y, q1)),
                              __fmul_rn(rc.z, q2));
        float inner = __fmul_rn(-2.0f, dot);
        float d = __fsub_rn(__fsub_rn(-rc.w, inner), xx3q);
        double key = packkey(d, idx);
        INS8(key);
      }
    }
  }
  // 8 extraction rounds across the wave (keys unique -> exact)
  double wk = 0.0;
#pragma unroll
  for (int r2 = 0; r2 < 8; ++r2) {
    double w = a0;
    MAX64(w);
    if (l == r2) wk = w;
    bool cns = (a0 == w);
    a0 = cns ? a1 : a0; a1 = cns ? a2 : a1; a2 = cns ? a3 : a2; a3 = cns ? a4 : a3;
    a4 = cns ? a5 : a4; a5 = cns ? a6 : a5; a6 = cns ? a7 : a6; a7 = cns ? -1.0 : a7;
  }
  if (l < 8) g_idxk[b * 32768 + l * 4096 + s] = keyidx(wk);   // rank-major (B,k,s)
}

// ---------------- BN partial sums (decoupled tail) ----------------
__global__ __launch_bounds__(256) void k_tail(const void* __restrict__ x,
                                              const void* __restrict__ Wpos,
                                              const void* __restrict__ bpos,
                                              const void* __restrict__ Wconv,
                                              const void* __restrict__ bconv) {
  __shared__ float sWpos[320], sbpos[32], sWconv[128], sbconv[32];
  __shared__ float sacc[16][128];
  __shared__ int sbx, sbw;
  int tid = threadIdx.x;
  if (tid == 0) { sbx = 0; sbw = 0; }
  __syncthreads();
  if (chk_bad(x, 1024, tid)) atomicOr(&sbx, 1);
  if (chk_bad(Wpos, 320, tid) | chk_bad(Wconv, 128, tid)) atomicOr(&sbw, 1);
  __syncthreads();
  const int f32 = sbx, wf32 = sbw;

  int id = blockIdx.x * 256 + tid;          // element in [0, 65536)
  int b = id >> 15, n = id & 32767;
  const int* fb = g_idxk + b * 32768;
  int base0 = b * C_ * P_;
  int p = fb[n] & (P_ - 1);
  int p0 = fb[n & ~7] & (P_ - 1);
  float xvv[4], pc3[3];
#pragma unroll
  for (int cc = 0; cc < 4; ++cc) xvv[cc] = ldany(x, base0 + cc * P_ + p, f32);
#pragma unroll
  for (int cc = 0; cc < 3; ++cc) pc3[cc] = ldany(x, base0 + cc * P_ + p0, f32);

  for (int i2 = tid; i2 < 320; i2 += 256) sWpos[i2] = ldany(Wpos, i2, wf32);
  if (tid < 128) sWconv[tid] = ldany(Wconv, tid, wf32);
  if (tid < 32) { sbpos[tid] = ldany(bpos, tid, wf32); sbconv[tid] = ldany(bconv, tid, wf32); }
  __syncthreads();

  float d0 = xvv[0] - pc3[0], d1 = xvv[1] - pc3[1], d2 = xvv[2] - pc3[2];
  float sq = d0 * d0 + d1 * d1 + d2 * d2;
  float temp = (sq > 0.0f) ? sqrtf(sq) : 0.0f;
  float pe[10] = {xvv[0], xvv[1], xvv[2], pc3[0], pc3[1], pc3[2], d0, d1, d2, temp};
#pragma unroll
  for (int o = 0; o < 64; ++o) {
    float v;
    if (o < 32) {
      v = sbconv[o];
#pragma unroll
      for (int cc = 0; cc < 4; ++cc) v = fmaf(sWconv[o * 4 + cc], xvv[cc], v);
    } else {
      v = sbpos[o - 32];
#pragma unroll
      for (int cc = 0; cc < 10; ++cc) v = fmaf(sWpos[(o - 32) * 10 + cc], pe[cc], v);
    }
    float sv = v, qv = v * v;
    for (int m = 1; m < 16; m <<= 1) { sv += __shfl_xor(sv, m, 16); qv += __shfl_xor(qv, m, 16); }
    if ((tid & 15) == 0) { sacc[tid >> 4][o * 2] = sv; sacc[tid >> 4][o * 2 + 1] = qv; }
  }
  __syncthreads();
  if (tid < 128) {
    float a = 0.f;
#pragma unroll
    for (int w = 0; w < 16; ++w) a += sacc[w][tid];
    g_partials[blockIdx.x * 128 + tid] = a;
  }
}

// ---------------- pass 2 : BN stats + recompute + attention + output ----------------
__global__ __launch_bounds__(256) void k_pass2(const void* __restrict__ x,
                                               const void* __restrict__ Wpos,
                                               const void* __restrict__ bpos,
                                               const void* __restrict__ Wconv,
                                               const void* __restrict__ bconv,
                                               const void* __restrict__ g1,
                                               const void* __restrict__ be1,
                                               const void* __restrict__ g2,
                                               const void* __restrict__ be2,
                                               const void* __restrict__ Wa1,
                                               const void* __restrict__ ba1,
                                               const void* __restrict__ Wa2,
                                               const void* __restrict__ ba2,
                                               const void* __restrict__ Wb1,
                                               const void* __restrict__ bb1,
                                               const void* __restrict__ Wb2,
                                               const void* __restrict__ bb2,
                                               void* __restrict__ out) {
  __shared__ float sWpos[320], sbpos[32], sWconv[128], sbconv[32];
  __shared__ float sWa1[2048], sba1[32], sWa2[32];
  __shared__ float sWb1[64 * 65];
  __shared__ float sbb1[64], sWb2[256], sbb2[64], sstats[128];
  __shared__ float sp2[2][128];
  __shared__ float sba2;
  __shared__ int sbx, sbw;
  int tid = threadIdx.x;
  if (tid == 0) { sbx = 0; sbw = 0; }
  __syncthreads();
  if (chk_bad(x, 1024, tid)) atomicOr(&sbx, 1);
  if (chk_bad(Wa1, 2048, tid) | chk_bad(Wb1, 4096, tid)) atomicOr(&sbw, 1);
  __syncthreads();
  int xf32 = sbx, wf32 = sbw;

  int g = blockIdx.x * 32 + (tid >> 3);
  int j = tid & 7;
  int b = g >> 12, i = g & (S_ - 1);
  int n = i * 8 + j;
  const int* fb = g_idxk + b * 32768;
  int xbase = b * C_ * P_;
  int p = fb[n] & (P_ - 1);
  int p0 = fb[n & ~7] & (P_ - 1);
  float xvv[4];
#pragma unroll
  for (int c = 0; c < 4; ++c) xvv[c] = ldany(x, xbase + c * P_ + p, xf32);
  float pc3[3];
#pragma unroll
  for (int c = 0; c < 3; ++c) pc3[c] = ldany(x, xbase + c * P_ + p0, xf32);
  float xc0 = ldany(x, xbase + p0, xf32);
  float xc1 = ldany(x, xbase + P_ + p0, xf32);
  float xc2 = ldany(x, xbase + 2 * P_ + p0, xf32);
  float xc3 = ldany(x, xbase + 3 * P_ + p0, xf32);

  {
    int slot = tid & 127, half = tid >> 7;
    float a0 = 0.f, a1 = 0.f;
    for (int blk = half * 128; blk < half * 128 + 128; blk += 2) {
      a0 += g_partials[blk * 128 + slot];
      a1 += g_partials[(blk + 1) * 128 + slot];
    }
    sp2[half][slot] = a0 + a1;
  }
  for (int i2 = tid; i2 < 320; i2 += 256) sWpos[i2] = ldany(Wpos, i2, wf32);
  if (tid < 128) sWconv[tid] = ldany(Wconv, tid, wf32);
  if (tid < 32) { sbpos[tid] = ldany(bpos, tid, wf32); sbconv[tid] = ldany(bconv, tid, wf32); }
  for (int i2 = tid; i2 < 2048; i2 += 256) sWa1[i2] = ldany(Wa1, i2, wf32);
  for (int i2 = tid; i2 < 4096; i2 += 256) sWb1[(i2 >> 6) * 65 + (i2 & 63)] = ldany(Wb1, i2, wf32);
  if (tid >= 32 && tid < 64) { sba1[tid - 32] = ldany(ba1, tid - 32, wf32); sWa2[tid - 32] = ldany(Wa2, tid - 32, wf32); }
  if (tid >= 64 && tid < 128) { sbb1[tid - 64] = ldany(bb1, tid - 64, wf32); sbb2[tid - 64] = ldany(bb2, tid - 64, wf32); }
  sWb2[tid] = ldany(Wb2, tid, wf32);
  if (tid == 0) sba2 = ldany(ba2, 0, wf32);
  __syncthreads();
  if (tid >= 128 && tid < 192) {
    int ch = tid - 128;
    float sum = sp2[0][ch * 2] + sp2[1][ch * 2];
    float sq = sp2[0][ch * 2 + 1] + sp2[1][ch * 2 + 1];
    float mean = sum * (1.0f / 65536.0f);
    float var = sq * (1.0f / 65536.0f) - mean * mean;
    int o = ch & 31;
    float gg = ldany(ch < 32 ? g1 : g2, o, wf32);
    float be = ldany(ch < 32 ? be1 : be2, o, wf32);
    float scale = gg / sqrtf(var + 1e-5f);
    sstats[ch * 2] = scale;
    sstats[ch * 2 + 1] = be - mean * scale;
  }
  __syncthreads();

  float d0 = xvv[0] - pc3[0], d1 = xvv[1] - pc3[1], d2 = xvv[2] - pc3[2];
  float sq = d0 * d0 + d1 * d1 + d2 * d2;
  float temp = (sq > 0.0f) ? sqrtf(sq) : 0.0f;
  float pe[10] = {xvv[0], xvv[1], xvv[2], pc3[0], pc3[1], pc3[2], d0, d1, d2, temp};
  float feat[64];
#pragma unroll
  for (int o = 0; o < 32; ++o) {
    float acc = sbconv[o];
#pragma unroll
    for (int c = 0; c < 4; ++c) acc = fmaf(sWconv[o * 4 + c], xvv[c], acc);
    feat[o] = acc;
  }
#pragma unroll
  for (int o = 0; o < 32; ++o) {
    float acc = sbpos[o];
#pragma unroll
    for (int c = 0; c < 10; ++c) acc = fmaf(sWpos[o * 10 + c], pe[c], acc);
    feat[32 + o] = acc;
  }
#pragma unroll
  for (int c = 0; c < 64; ++c) {
    float v = fmaf(feat[c], sstats[c * 2], sstats[c * 2 + 1]);
    feat[c] = (v >= 0.f) ? v : 0.2f * v;
  }
  float att = sba2;
#pragma unroll 4
  for (int h = 0; h < 32; ++h) {
    float a0 = 0.f, a1 = 0.f, a2 = 0.f, a3 = 0.f;
#pragma unroll
    for (int c = 0; c < 64; c += 4) {
      a0 = fmaf(sWa1[h * 64 + c],     feat[c],     a0);
      a1 = fmaf(sWa1[h * 64 + c + 1], feat[c + 1], a1);
      a2 = fmaf(sWa1[h * 64 + c + 2], feat[c + 2], a2);
      a3 = fmaf(sWa1[h * 64 + c + 3], feat[c + 3], a3);
    }
    float acc = sba1[h] + ((a0 + a1) + (a2 + a3));
    acc = (acc >= 0.f) ? acc : 0.2f * acc;
    att = fmaf(sWa2[h], acc, att);
  }
  float mxv = att;
  for (int mk = 1; mk < 8; mk <<= 1) mxv = fmaxf(mxv, __shfl_xor(mxv, mk, 8));
  float e = expf(att - mxv);
  float se = e;
  for (int mk = 1; mk < 8; mk <<= 1) se += __shfl_xor(se, mk, 8);
  float a = e / se;
#pragma unroll
  for (int c = 0; c < 64; ++c) {
    float w = feat[c] * a;
    w += __shfl_xor(w, 1, 8);
    w += __shfl_xor(w, 2, 8);
    w += __shfl_xor(w, 4, 8);
    feat[c] = w;
  }
  int obase = b * 69 * S_;
#pragma unroll
  for (int oc = 0; oc < 8; ++oc) {
    int o = j * 8 + oc;
    float a0 = sbb1[o], a1 = 0.f, a2 = 0.f, a3 = 0.f;
#pragma unroll
    for (int c = 0; c < 64; c += 4) {
      a0 = fmaf(sWb1[o * 65 + c],     feat[c],     a0);
      a1 = fmaf(sWb1[o * 65 + c + 1], feat[c + 1], a1);
      a2 = fmaf(sWb1[o * 65 + c + 2], feat[c + 2], a2);
      a3 = fmaf(sWb1[o * 65 + c + 3], feat[c + 3], a3);
    }
    float acc = (a0 + a1) + (a2 + a3);
    float acc2 = sbb2[o];
    acc2 = fmaf(sWb2[o * 4 + 0], xc0, acc2);
    acc2 = fmaf(sWb2[o * 4 + 1], xc1, acc2);
    acc2 = fmaf(sWb2[o * 4 + 2], xc2, acc2);
    acc2 = fmaf(sWb2[o * 4 + 3], xc3, acc2);
    float r = acc + acc2;
    r = (r >= 0.f) ? r : 0.01f * r;
    int oi = obase + (5 + o) * S_ + i;
    if (xf32) ((float*)out)[oi] = r; else ((u16*)out)[oi] = f2bf(r);
  }
  if (j == 0) {
#pragma unroll
    for (int c = 0; c < 5; ++c) {
      int oi = obase + c * S_ + i;
      if (xf32) ((float*)out)[oi] = ((const float*)x)[xbase + c * P_ + p0];
      else      ((u16*)out)[oi]   = ((const u16*)x)[xbase + c * P_ + p0];
    }
  }
}

extern "C" void kernel_launch(void* const* d_in, const int* in_sizes, int n_in,
                              void* d_out, int out_size, void* d_ws, size_t ws_size,
                              hipStream_t stream) {
  const void* x     = d_in[0];
  const void* Wpos  = d_in[1];
  const void* bpos  = d_in[2];
  const void* g2    = d_in[3];
  const void* be2   = d_in[4];
  const void* Wconv = d_in[5];
  const void* bconv = d_in[6];
  const void* g1    = d_in[7];
  const void* be1   = d_in[8];
  const void* Wa1   = d_in[9];
  const void* ba1   = d_in[10];
  const void* Wa2   = d_in[11];
  const void* ba2   = d_in[12];
  const void* Wb1   = d_in[13];
  const void* bb1   = d_in[14];
  const void* Wb2   = d_in[15];
  const void* bb2   = d_in[16];
  (void)d_ws; (void)ws_size; (void)in_sizes; (void)n_in;

  hipLaunchKernelGGL(k_prep,    dim3(2),    dim3(256), 0, stream, x);
  hipLaunchKernelGGL(k_hist,    dim3(32),   dim3(256), 0, stream, x);
  hipLaunchKernelGGL(k_scan,    dim3(2),    dim3(256), 0, stream);
  hipLaunchKernelGGL(k_scatter, dim3(32),   dim3(256), 0, stream, x);
  hipLaunchKernelGGL(k_dt,      dim3(2),    dim3(256), 0, stream);
  hipLaunchKernelGGL(k_knn2,    dim3(2048), dim3(256), 0, stream, x);
  hipLaunchKernelGGL(k_tail,    dim3(256),  dim3(256), 0, stream, x,
                     Wpos, bpos, Wconv, bconv);
  hipLaunchKernelGGL(k_pass2,   dim3(256),  dim3(256), 0, stream, x,
                     Wpos, bpos, Wconv, bconv, g1, be1, g2, be2,
                     Wa1, ba1, Wa2, ba2, Wb1, bb1, Wb2, bb2, d_out);
}

// Round 8
// 366.549 us; speedup vs baseline: 1.7009x; 1.0071x over previous
//
#include <hip/hip_runtime.h>
#include <math.h>

#define B_ 2
#define P_ 16384
#define C_ 5
#define S_ 4096
#define KNN_ 8
#define L_ 64

typedef unsigned short u16;
typedef unsigned int u32;
typedef unsigned long long u64;

// ---- static scratch: fully rewritten every call before any read ----
__device__ int    g_idxk[B_ * KNN_ * S_];
__device__ float  g_partials[256 * 128];   // [tail_block][slot], wave-coalesced
__device__ float  g_mnmx[B_][5];           // mn0,mx0,mn1,mx1,amax^2
__device__ int    g_hist[B_ * 4097];       // bin starts after scan (+sentinel)
__device__ int    g_cursor[B_ * 4096];     // scatter cursors
__device__ int    g_binof[B_ * P_];        // bin of each point
__device__ int    g_dt[B_ * 4096];         // Chebyshev dist to nearest occupied bin
__device__ u64    g_mask[B_ * 64];         // row occupancy bitmasks
__device__ float4 g_recA[B_ * P_];         // (v0, v1, xx2d, idx_bits)
__device__ float4 g_recB[B_ * P_];         // (v0, v1, v2, xx3)
__device__ u16    g_idxsc[B_ * P_];        // original idx per scattered record

__device__ __forceinline__ float bf2f(u16 u) {
  union { u32 i; float f; } c; c.i = ((u32)u) << 16; return c.f;
}
__device__ __forceinline__ u16 f2bf(float f) {
  union { float f; u32 i; } c; c.f = f;
  u32 r = c.i + 0x7fffu + ((c.i >> 16) & 1u);
  return (u16)(r >> 16);
}
__device__ __forceinline__ float ldany(const void* p, int i, int f32) {
  return f32 ? ((const float*)p)[i] : bf2f(((const u16*)p)[i]);
}

// ---- (d, idx) -> fixed-exponent positive double; order == (d desc, idx asc); unique ----
__device__ __forceinline__ double packkey(float d, int idx) {
  u32 bits = __float_as_uint(d);
  u32 key = bits ^ ((u32)(((int)bits) >> 31) | 0x80000000u);  // monotone u32 map of f32
  int hi = (int)(0x3FF00000u | (key >> 12));
  int lo = (int)((key << 20) | ((u32)(16383 - idx) << 6));
  return __hiloint2double(hi, lo);
}
__device__ __forceinline__ int keyidx(double w) {
  return 16383 - (int)(((u32)__double2loint(w) >> 6) & 16383u);
}
// inverse of the monotone map: recover the float d stored in a key
__device__ __forceinline__ float keyd(double w) {
  u32 hi = (u32)__double2hiint(w), lo = (u32)__double2loint(w);
  u32 key = (hi << 12) | (lo >> 20);
  u32 mask = (u32)(((int)key) >> 31);
  u32 bits = key ^ ((~mask) | 0x80000000u);
  return __uint_as_float(bits);
}

__device__ __forceinline__ int chk_bad(const void* p, int n, int tid) {
  int bad = 0;
  for (int i = tid; i < n; i += 256) {
    float f = bf2f(((const u16*)p)[i]);
    if (!(f == f) || fabsf(f) > 1024.0f) bad = 1;
  }
  return bad;
}

// named-register sorted-desc top-8 insert
#define INS8(key)                                                        \
  do {                                                                   \
    if ((key) > a7) {                                                    \
      double t_ = (key), h_;                                             \
      h_ = fmax(a0, t_); t_ = fmin(a0, t_); a0 = h_;                     \
      h_ = fmax(a1, t_); t_ = fmin(a1, t_); a1 = h_;                     \
      h_ = fmax(a2, t_); t_ = fmin(a2, t_); a2 = h_;                     \
      h_ = fmax(a3, t_); t_ = fmin(a3, t_); a3 = h_;                     \
      h_ = fmax(a4, t_); t_ = fmin(a4, t_); a4 = h_;                     \
      h_ = fmax(a5, t_); t_ = fmin(a5, t_); a5 = h_;                     \
      h_ = fmax(a6, t_); t_ = fmin(a6, t_); a6 = h_;                     \
      a7 = fmax(a7, t_);                                                 \
    }                                                                    \
  } while (0)

#define MAX64(w)                                                         \
  do {                                                                   \
    w = fmax(w, __shfl_xor(w, 1, 64));                                   \
    w = fmax(w, __shfl_xor(w, 2, 64));                                   \
    w = fmax(w, __shfl_xor(w, 4, 64));                                   \
    w = fmax(w, __shfl_xor(w, 8, 64));                                   \
    w = fmax(w, __shfl_xor(w, 16, 64));                                  \
    w = fmax(w, __shfl_xor(w, 32, 64));                                  \
  } while (0)

// ring cell enumeration (Chebyshev ring R, t-th cell of 8R)
__device__ __forceinline__ void ringcell(int R, int t, int cx, int cy, int& X, int& Y) {
  int side = 2 * R + 1;
  if (t < side)          { X = cx - R + t;          Y = cy - R; }
  else if (t < 2 * side) { X = cx - R + (t - side); Y = cy + R; }
  else {
    int u = t - 2 * side, m2 = 2 * R - 1;
    if (u < m2) { X = cx - R; Y = cy - R + 1 + u; }
    else        { X = cx + R; Y = cy - R + 1 + (u - m2); }
  }
}

// ---------------- prep: min/max + |max| bound, zero histogram ----------------
__global__ __launch_bounds__(256) void k_prep(const void* __restrict__ xv) {
  __shared__ int sbad;
  __shared__ float sred[4][5];
  int tid = threadIdx.x, b = blockIdx.x;
  if (tid == 0) sbad = 0;
  __syncthreads();
  if (chk_bad(xv, 1024, tid)) atomicOr(&sbad, 1);
  __syncthreads();
  const int f32 = sbad;
  int base0 = b * C_ * P_, base1 = base0 + P_, base2 = base1 + P_;
  float mn0 = INFINITY, mx0 = -INFINITY, mn1 = INFINITY, mx1 = -INFINITY, am = 0.f;
  for (int p = tid; p < P_; p += 256) {
    float v0 = ldany(xv, base0 + p, f32);
    float v1 = ldany(xv, base1 + p, f32);
    float v2 = ldany(xv, base2 + p, f32);
    mn0 = fminf(mn0, v0); mx0 = fmaxf(mx0, v0);
    mn1 = fminf(mn1, v1); mx1 = fmaxf(mx1, v1);
    am = fmaxf(am, fabsf(v2));
  }
  for (int off = 32; off; off >>= 1) {
    mn0 = fminf(mn0, __shfl_down(mn0, off)); mx0 = fmaxf(mx0, __shfl_down(mx0, off));
    mn1 = fminf(mn1, __shfl_down(mn1, off)); mx1 = fmaxf(mx1, __shfl_down(mx1, off));
    am = fmaxf(am, __shfl_down(am, off));
  }
  int l = tid & 63, g = tid >> 6;
  if (l == 0) {
    sred[g][0] = mn0; sred[g][1] = mx0; sred[g][2] = mn1; sred[g][3] = mx1; sred[g][4] = am;
  }
  __syncthreads();
  if (tid == 0) {
    float a0 = fminf(fminf(sred[0][0], sred[1][0]), fminf(sred[2][0], sred[3][0]));
    float a1 = fmaxf(fmaxf(sred[0][1], sred[1][1]), fmaxf(sred[2][1], sred[3][1]));
    float a2 = fminf(fminf(sred[0][2], sred[1][2]), fminf(sred[2][2], sred[3][2]));
    float a3 = fmaxf(fmaxf(sred[0][3], sred[1][3]), fmaxf(sred[2][3], sred[3][3]));
    float a4 = fmaxf(fmaxf(sred[0][4], sred[1][4]), fmaxf(sred[2][4], sred[3][4]));
    float aa = fmaxf(fmaxf(fabsf(a0), fabsf(a1)), fmaxf(fmaxf(fabsf(a2), fabsf(a3)), a4));
    g_mnmx[b][0] = a0; g_mnmx[b][1] = a1; g_mnmx[b][2] = a2; g_mnmx[b][3] = a3;
    g_mnmx[b][4] = aa * aa;
  }
  for (int i2 = tid; i2 < 4097; i2 += 256) g_hist[b * 4097 + i2] = 0;
}

// ---------------- histogram + per-point bin ----------------
__global__ __launch_bounds__(256) void k_hist(const void* __restrict__ xv) {
  __shared__ int sbad;
  int tid = threadIdx.x, blk = blockIdx.x;
  if (tid == 0) sbad = 0;
  __syncthreads();
  if (chk_bad(xv, 1024, tid)) atomicOr(&sbad, 1);
  __syncthreads();
  const int f32 = sbad;
  int b = blk >> 4;
  int pb = (blk & 15) * 1024;
  int base0 = b * C_ * P_, base1 = base0 + P_;
  float mn0 = g_mnmx[b][0], mx0 = g_mnmx[b][1], mn1 = g_mnmx[b][2], mx1 = g_mnmx[b][3];
  float r0 = __fsub_rn(mx0, mn0), r1 = __fsub_rn(mx1, mn1);
  float inv0 = (r0 > 0.f) ? 64.0f / r0 : 0.f;
  float inv1 = (r1 > 0.f) ? 64.0f / r1 : 0.f;
  for (int q = 0; q < 4; ++q) {
    int i = pb + q * 256 + tid;
    float v0 = ldany(xv, base0 + i, f32);
    float v1 = ldany(xv, base1 + i, f32);
    int bx = (int)fminf(fmaxf((v0 - mn0) * inv0, 0.f), 63.f);
    int by = (int)fminf(fmaxf((v1 - mn1) * inv1, 0.f), 63.f);
    int bin = by * 64 + bx;
    g_binof[b * P_ + i] = bin;
    atomicAdd(&g_hist[b * 4097 + bin], 1);
  }
}

// ---------------- exclusive prefix over 4096 bins (per b) ----------------
__global__ __launch_bounds__(256) void k_scan() {
  __shared__ int part[256];
  int b = blockIdx.x, t = threadIdx.x;
  int loc[16]; int s0 = 0;
  for (int q = 0; q < 16; ++q) { loc[q] = g_hist[b * 4097 + t * 16 + q]; s0 += loc[q]; }
  part[t] = s0;
  __syncthreads();
  for (int d2 = 1; d2 < 256; d2 <<= 1) {
    int v = (t >= d2) ? part[t - d2] : 0;
    __syncthreads();
    part[t] += v;
    __syncthreads();
  }
  int run = (t == 0) ? 0 : part[t - 1];
  for (int q = 0; q < 16; ++q) {
    g_hist[b * 4097 + t * 16 + q] = run;
    g_cursor[b * 4096 + t * 16 + q] = run;
    run += loc[q];
  }
  if (t == 0) g_hist[b * 4097 + 4096] = P_;
}

// ---------------- scatter points into binned records ----------------
__global__ __launch_bounds__(256) void k_scatter(const void* __restrict__ xv) {
  __shared__ int sbad;
  int tid = threadIdx.x, blk = blockIdx.x;
  if (tid == 0) sbad = 0;
  __syncthreads();
  if (chk_bad(xv, 1024, tid)) atomicOr(&sbad, 1);
  __syncthreads();
  const int f32 = sbad;
  int b = blk >> 4;
  int pb = (blk & 15) * 1024;
  int base0 = b * C_ * P_, base1 = base0 + P_, base2 = base1 + P_;
  for (int q = 0; q < 4; ++q) {
    int i = pb + q * 256 + tid;
    float a0 = ldany(xv, base0 + i, f32);
    float a1 = ldany(xv, base1 + i, f32);
    float a2 = ldany(xv, base2 + i, f32);
    // EXACT expression trees matching the verified brute-force staging:
    float xx2d = __fadd_rn(__fmul_rn(a0, a0), __fmul_rn(a1, a1));
    float xx3  = __fadd_rn(__fadd_rn(__fmul_rn(a0, a0), __fmul_rn(a1, a1)), __fmul_rn(a2, a2));
    int bin = g_binof[b * P_ + i];
    int pos = atomicAdd(&g_cursor[b * 4096 + bin], 1);
    g_recA[(b << 14) + pos] = make_float4(a0, a1, xx2d, __int_as_float(i));
    g_recB[(b << 14) + pos] = make_float4(a0, a1, a2, xx3);
    g_idxsc[(b << 14) + pos] = (u16)i;
  }
}

// ---------------- Chebyshev distance transform + occupancy masks ----------------
__global__ __launch_bounds__(256) void k_dt() {
  __shared__ u64 occm[64];
  __shared__ short rowd[64][64];
  int b = blockIdx.x, t = threadIdx.x;
  if (t < 64) {
    u64 m = 0ull;
    const int* h = g_hist + b * 4097 + t * 64;
    for (int x = 0; x < 64; ++x)
      if (h[x + 1] > h[x]) m |= (1ull << x);
    occm[t] = m;
    g_mask[b * 64 + t] = m;                 // publish for k_knn2 (conflict-free reload)
  }
  __syncthreads();
#pragma unroll
  for (int q = 0; q < 16; ++q) {            // rowdist for 16 cells per thread
    int c = q * 256 + t, y = c >> 6, x = c & 63;
    u64 m = occm[y];
    int rd = 127;
    if (m) {
      u64 hi = m >> x;
      int dhi = hi ? (__ffsll((long long)hi) - 1) : 127;
      u64 lo = (x < 63) ? (m & (((u64)1 << (x + 1)) - 1)) : m;
      int dlo = lo ? (x - (63 - __clzll((long long)lo))) : 127;
      rd = min(dhi, dlo);
    }
    rowd[y][x] = (short)rd;
  }
  __syncthreads();
#pragma unroll
  for (int q = 0; q < 16; ++q) {            // column fold: dt = min_y' max(|dy|, rowd)
    int c = q * 256 + t, y = c >> 6, x = c & 63;
    int best = 127;
    for (int dy = 0; dy < 64; ++dy) {
      if (dy >= best) break;
      int y1 = y - dy, y2 = y + dy;
      if (y1 >= 0) { int v = rowd[y1][x]; best = min(best, (dy > v) ? dy : v); }
      if (dy && y2 < 64) { int v = rowd[y2][x]; best = min(best, (dy > v) ? dy : v); }
    }
    g_dt[(b << 12) + c] = best;
  }
}

// ---------------- binned exact kNN: one 64-lane wave per query ----------------
// Lazy bounds: exact union best (t1) / union 8th (t8) kept broadcast in regs;
// recomputed only when a ring added a candidate that beats them.
__global__ __launch_bounds__(256, 6) void k_knn2(const void* __restrict__ xv) {
  __shared__ int shist[4097];
  __shared__ u64 smask[64];
  __shared__ int sbad;
  int tid = threadIdx.x;
  if (tid == 0) sbad = 0;
  __syncthreads();
  if (chk_bad(xv, 1024, tid)) atomicOr(&sbad, 1);
  __syncthreads();
  const int f32 = sbad;

  int blk = blockIdx.x;
  int b = blk >> 10;                         // 1024 blocks per batch element
  for (int i2 = tid; i2 < 4097; i2 += 256) shist[i2] = g_hist[b * 4097 + i2];
  if (tid < 64) smask[tid] = g_mask[b * 64 + tid];   // coalesced, conflict-free
  __syncthreads();

  int l = tid & 63;                          // lane within the query's wave
  int grp = l >> 3, lo = l & 7;
  int q = blk * 4 + (tid >> 6);              // query id 0..8191 (b == q>>12)
  int s = q & (S_ - 1);
  int base0 = b * C_ * P_, base1 = base0 + P_, base2 = base1 + P_;

  float mn0 = g_mnmx[b][0], mx0 = g_mnmx[b][1], mn1 = g_mnmx[b][2], mx1 = g_mnmx[b][3];
  float margin = 2e-5f * g_mnmx[b][4];
  float r0 = __fsub_rn(mx0, mn0), r1 = __fsub_rn(mx1, mn1);
  float w0 = r0 * 0.015625f, w1 = r1 * 0.015625f;
  float wmin = fminf(w0, w1) * 0.999f;       // conservative slack vs fp rounding
  const float4* recA = g_recA + (b << 14);
  const float4* recB = g_recB + (b << 14);

  // ---- phase A: nearest (2D) to lattice node s ----
  float mm0 = (float)(s & (L_ - 1)) * 0.015625f;
  float mm1 = (float)(s >> 6) * 0.015625f;
  float ps0 = __fadd_rn(__fmul_rn(mm0, r0), mn0);
  float ps1 = __fadd_rn(__fmul_rn(mm1, r1), mn1);
  float xx2q = __fadd_rn(__fmul_rn(ps0, ps0), __fmul_rn(ps1, ps1));
  int bqx = s & 63, bqy = s >> 6;            // exact bin identity
  int R0 = g_dt[(b << 12) + s];              // rings < R0 provably empty
  double bestA = -1.0;
  if (R0 <= 1) {                             // 3x3 core: all 64 lanes split records
#pragma unroll
    for (int dy = -1; dy <= 1; ++dy) {
#pragma unroll
      for (int dx = -1; dx <= 1; ++dx) {
        int X = bqx + dx, Y = bqy + dy;
        if ((unsigned)X > 63u || (unsigned)Y > 63u) continue;
        if (!((smask[Y] >> X) & 1ull)) continue;
        int bin = Y * 64 + X;
        int st = shist[bin], en = shist[bin + 1];
        for (int j2 = st + l; j2 < en; j2 += 64) {
          float4 rc = recA[j2];
          float dot = __fadd_rn(__fmul_rn(rc.x, ps0), __fmul_rn(rc.y, ps1));
          float inner = __fmul_rn(-2.0f, dot);
          float d = __fsub_rn(__fsub_rn(-rc.z, inner), xx2q);
          bestA = fmax(bestA, packkey(d, __float_as_int(rc.w)));
        }
      }
    }
  }
  double t1 = bestA;                         // exact union best (broadcast)
  MAX64(t1);
  for (int R = (R0 < 2 ? 2 : R0); R < 64; ++R) {
    if (t1 >= 1.0) {
      float lb = (float)(R - 1) * wmin;
      float ub = __fadd_rn(-(lb * lb), margin);
      if (ub < keyd(t1)) break;
    }
    int cnt = 8 * R;
    for (int t = grp; t < cnt; t += 8) {
      int X, Y;
      ringcell(R, t, bqx, bqy, X, Y);
      if ((unsigned)X > 63u || (unsigned)Y > 63u) continue;
      if (!((smask[Y] >> X) & 1ull)) continue;
      int bin = Y * 64 + X;
      int st = shist[bin], en = shist[bin + 1];
      for (int j2 = st + lo; j2 < en; j2 += 8) {
        float4 rc = recA[j2];
        float dot = __fadd_rn(__fmul_rn(rc.x, ps0), __fmul_rn(rc.y, ps1));
        float inner = __fmul_rn(-2.0f, dot);
        float d = __fsub_rn(__fsub_rn(-rc.z, inner), xx2q);
        bestA = fmax(bestA, packkey(d, __float_as_int(rc.w)));
      }
    }
    if (__any(bestA > t1)) { t1 = bestA; MAX64(t1); }   // lazy exact refresh
  }
  int qi = keyidx(t1) & (P_ - 1);

  // ---- phase B: top-8 (3D) from data point qi (its bin occupied) ----
  float q0 = ldany(xv, base0 + qi, f32);
  float q1 = ldany(xv, base1 + qi, f32);
  float q2 = ldany(xv, base2 + qi, f32);
  float xx3q = __fadd_rn(__fadd_rn(__fmul_rn(q0, q0), __fmul_rn(q1, q1)), __fmul_rn(q2, q2));
  int qbin = g_binof[b * P_ + qi];
  int cx = qbin & 63, cy = qbin >> 6;
  double a0 = -1.0, a1 = -1.0, a2 = -1.0, a3 = -1.0,
         a4 = -1.0, a5 = -1.0, a6 = -1.0, a7 = -1.0;
#pragma unroll
  for (int dy = -1; dy <= 1; ++dy) {         // 3x3 core: 64-lane record split
#pragma unroll
    for (int dx = -1; dx <= 1; ++dx) {
      int X = cx + dx, Y = cy + dy;
      if ((unsigned)X > 63u || (unsigned)Y > 63u) continue;
      if (!((smask[Y] >> X) & 1ull)) continue;
      int bin = Y * 64 + X;
      int st = shist[bin], en = shist[bin + 1];
      for (int j2 = st + l; j2 < en; j2 += 64) {
        float4 rc = recB[j2];
        int idx = (int)g_idxsc[(b << 14) + j2];
        float dot = __fadd_rn(__fadd_rn(__fmul_rn(rc.x, q0), __fmul_rn(rc.y, q1)),
                              __fmul_rn(rc.z, q2));
        float inner = __fmul_rn(-2.0f, dot);
        float d = __fsub_rn(__fsub_rn(-rc.w, inner), xx3q);
        double key = packkey(d, idx);
        INS8(key);
      }
    }
  }
  // exact union 8th (broadcast), computed on copies
  double t8;
  {
    double c0 = a0, c1 = a1, c2 = a2, c3 = a3, c4 = a4, c5 = a5, c6 = a6, c7 = a7;
    double w = -1.0;
#pragma unroll
    for (int r2 = 0; r2 < 8; ++r2) {
      w = c0;
      MAX64(w);
      bool cns = (c0 == w);
      c0 = cns ? c1 : c0; c1 = cns ? c2 : c1; c2 = cns ? c3 : c2; c3 = cns ? c4 : c3;
      c4 = cns ? c5 : c4; c5 = cns ? c6 : c5; c6 = cns ? c7 : c6; c7 = cns ? -1.0 : c7;
    }
    t8 = w;
  }
  for (int R = 2; R < 64; ++R) {
    if (t8 >= 1.0) {
      float lb = (float)(R - 1) * wmin;      // 2D lower bound of 3D distance
      float ub = __fadd_rn(-(lb * lb), margin);
      if (ub < keyd(t8)) break;
    }
    bool added = false;
    int cnt = 8 * R;
    for (int t = grp; t < cnt; t += 8) {
      int X, Y;
      ringcell(R, t, cx, cy, X, Y);
      if ((unsigned)X > 63u || (unsigned)Y > 63u) continue;
      if (!((smask[Y] >> X) & 1ull)) continue;
      int bin = Y * 64 + X;
      int st = shist[bin], en = shist[bin + 1];
      for (int j2 = st + lo; j2 < en; j2 += 8) {
        float4 rc = recB[j2];
        int idx = (int)g_idxsc[(b << 14) + j2];
        float dot = __fadd_rn(__fadd_rn(__fmul_rn(rc.x, q0), __fmul_rn(rc.y, q1)),
                              __fmul_rn(rc.z, q2));
        float inner = __fmul_rn(-2.0f, dot);
        float d = __fsub_rn(__fsub_rn(-rc.w, inner), xx3q);
        double key = packkey(d, idx);
        added = added || (key > t8);
        INS8(key);
      }
    }
    if (__any(added)) {                      // lazy exact refresh of union 8th
      double c0 = a0, c1 = a1, c2 = a2, c3 = a3, c4 = a4, c5 = a5, c6 = a6, c7 = a7;
      double w = -1.0;
#pragma unroll
      for (int r2 = 0; r2 < 8; ++r2) {
        w = c0;
        MAX64(w);
        bool cns = (c0 == w);
        c0 = cns ? c1 : c0; c1 = cns ? c2 : c1; c2 = cns ? c3 : c2; c3 = cns ? c4 : c3;
        c4 = cns ? c5 : c4; c5 = cns ? c6 : c5; c6 = cns ? c7 : c6; c7 = cns ? -1.0 : c7;
      }
      t8 = w;
    }
  }
  // 8 extraction rounds across the wave (keys unique -> exact)
  double wk = 0.0;
#pragma unroll
  for (int r2 = 0; r2 < 8; ++r2) {
    double w = a0;
    MAX64(w);
    if (l == r2) wk = w;
    bool cns = (a0 == w);
    a0 = cns ? a1 : a0; a1 = cns ? a2 : a1; a2 = cns ? a3 : a2; a3 = cns ? a4 : a3;
    a4 = cns ? a5 : a4; a5 = cns ? a6 : a5; a6 = cns ? a7 : a6; a7 = cns ? -1.0 : a7;
  }
  if (l < 8) g_idxk[b * 32768 + l * 4096 + s] = keyidx(wk);   // rank-major (B,k,s)
}

// ---------------- BN partial sums (decoupled tail) ----------------
__global__ __launch_bounds__(256) void k_tail(const void* __restrict__ x,
                                              const void* __restrict__ Wpos,
                                              const void* __restrict__ bpos,
                                              const void* __restrict__ Wconv,
                                              const void* __restrict__ bconv) {
  __shared__ float sWpos[320], sbpos[32], sWconv[128], sbconv[32];
  __shared__ float sacc[16][128];
  __shared__ int sbx, sbw;
  int tid = threadIdx.x;
  if (tid == 0) { sbx = 0; sbw = 0; }
  __syncthreads();
  if (chk_bad(x, 1024, tid)) atomicOr(&sbx, 1);
  if (chk_bad(Wpos, 320, tid) | chk_bad(Wconv, 128, tid)) atomicOr(&sbw, 1);
  __syncthreads();
  const int f32 = sbx, wf32 = sbw;

  int id = blockIdx.x * 256 + tid;          // element in [0, 65536)
  int b = id >> 15, n = id & 32767;
  const int* fb = g_idxk + b * 32768;
  int base0 = b * C_ * P_;
  int p = fb[n] & (P_ - 1);
  int p0 = fb[n & ~7] & (P_ - 1);
  float xvv[4], pc3[3];
#pragma unroll
  for (int cc = 0; cc < 4; ++cc) xvv[cc] = ldany(x, base0 + cc * P_ + p, f32);
#pragma unroll
  for (int cc = 0; cc < 3; ++cc) pc3[cc] = ldany(x, base0 + cc * P_ + p0, f32);

  for (int i2 = tid; i2 < 320; i2 += 256) sWpos[i2] = ldany(Wpos, i2, wf32);
  if (tid < 128) sWconv[tid] = ldany(Wconv, tid, wf32);
  if (tid < 32) { sbpos[tid] = ldany(bpos, tid, wf32); sbconv[tid] = ldany(bconv, tid, wf32); }
  __syncthreads();

  float d0 = xvv[0] - pc3[0], d1 = xvv[1] - pc3[1], d2 = xvv[2] - pc3[2];
  float sq = d0 * d0 + d1 * d1 + d2 * d2;
  float temp = (sq > 0.0f) ? sqrtf(sq) : 0.0f;
  float pe[10] = {xvv[0], xvv[1], xvv[2], pc3[0], pc3[1], pc3[2], d0, d1, d2, temp};
#pragma unroll
  for (int o = 0; o < 64; ++o) {
    float v;
    if (o < 32) {
      v = sbconv[o];
#pragma unroll
      for (int cc = 0; cc < 4; ++cc) v = fmaf(sWconv[o * 4 + cc], xvv[cc], v);
    } else {
      v = sbpos[o - 32];
#pragma unroll
      for (int cc = 0; cc < 10; ++cc) v = fmaf(sWpos[(o - 32) * 10 + cc], pe[cc], v);
    }
    float sv = v, qv = v * v;
    for (int m = 1; m < 16; m <<= 1) { sv += __shfl_xor(sv, m, 16); qv += __shfl_xor(qv, m, 16); }
    if ((tid & 15) == 0) { sacc[tid >> 4][o * 2] = sv; sacc[tid >> 4][o * 2 + 1] = qv; }
  }
  __syncthreads();
  if (tid < 128) {
    float a = 0.f;
#pragma unroll
    for (int w = 0; w < 16; ++w) a += sacc[w][tid];
    g_partials[blockIdx.x * 128 + tid] = a;
  }
}

// ---------------- pass 2 : BN stats + recompute + attention + output ----------------
__global__ __launch_bounds__(256) void k_pass2(const void* __restrict__ x,
                                               const void* __restrict__ Wpos,
                                               const void* __restrict__ bpos,
                                               const void* __restrict__ Wconv,
                                               const void* __restrict__ bconv,
                                               const void* __restrict__ g1,
                                               const void* __restrict__ be1,
                                               const void* __restrict__ g2,
                                               const void* __restrict__ be2,
                                               const void* __restrict__ Wa1,
                                               const void* __restrict__ ba1,
                                               const void* __restrict__ Wa2,
                                               const void* __restrict__ ba2,
                                               const void* __restrict__ Wb1,
                                               const void* __restrict__ bb1,
                                               const void* __restrict__ Wb2,
                                               const void* __restrict__ bb2,
                                               void* __restrict__ out) {
  __shared__ float sWpos[320], sbpos[32], sWconv[128], sbconv[32];
  __shared__ float sWa1[2048], sba1[32], sWa2[32];
  __shared__ float sWb1[64 * 65];
  __shared__ float sbb1[64], sWb2[256], sbb2[64], sstats[128];
  __shared__ float sp2[2][128];
  __shared__ float sba2;
  __shared__ int sbx, sbw;
  int tid = threadIdx.x;
  if (tid == 0) { sbx = 0; sbw = 0; }
  __syncthreads();
  if (chk_bad(x, 1024, tid)) atomicOr(&sbx, 1);
  if (chk_bad(Wa1, 2048, tid) | chk_bad(Wb1, 4096, tid)) atomicOr(&sbw, 1);
  __syncthreads();
  int xf32 = sbx, wf32 = sbw;

  int g = blockIdx.x * 32 + (tid >> 3);
  int j = tid & 7;
  int b = g >> 12, i = g & (S_ - 1);
  int n = i * 8 + j;
  const int* fb = g_idxk + b * 32768;
  int xbase = b * C_ * P_;
  int p = fb[n] & (P_ - 1);
  int p0 = fb[n & ~7] & (P_ - 1);
  float xvv[4];
#pragma unroll
  for (int c = 0; c < 4; ++c) xvv[c] = ldany(x, xbase + c * P_ + p, xf32);
  float pc3[3];
#pragma unroll
  for (int c = 0; c < 3; ++c) pc3[c] = ldany(x, xbase + c * P_ + p0, xf32);
  float xc0 = ldany(x, xbase + p0, xf32);
  float xc1 = ldany(x, xbase + P_ + p0, xf32);
  float xc2 = ldany(x, xbase + 2 * P_ + p0, xf32);
  float xc3 = ldany(x, xbase + 3 * P_ + p0, xf32);

  {
    int slot = tid & 127, half = tid >> 7;
    float a0 = 0.f, a1 = 0.f;
    for (int blk = half * 128; blk < half * 128 + 128; blk += 2) {
      a0 += g_partials[blk * 128 + slot];
      a1 += g_partials[(blk + 1) * 128 + slot];
    }
    sp2[half][slot] = a0 + a1;
  }
  for (int i2 = tid; i2 < 320; i2 += 256) sWpos[i2] = ldany(Wpos, i2, wf32);
  if (tid < 128) sWconv[tid] = ldany(Wconv, tid, wf32);
  if (tid < 32) { sbpos[tid] = ldany(bpos, tid, wf32); sbconv[tid] = ldany(bconv, tid, wf32); }
  for (int i2 = tid; i2 < 2048; i2 += 256) sWa1[i2] = ldany(Wa1, i2, wf32);
  for (int i2 = tid; i2 < 4096; i2 += 256) sWb1[(i2 >> 6) * 65 + (i2 & 63)] = ldany(Wb1, i2, wf32);
  if (tid >= 32 && tid < 64) { sba1[tid - 32] = ldany(ba1, tid - 32, wf32); sWa2[tid - 32] = ldany(Wa2, tid - 32, wf32); }
  if (tid >= 64 && tid < 128) { sbb1[tid - 64] = ldany(bb1, tid - 64, wf32); sbb2[tid - 64] = ldany(bb2, tid - 64, wf32); }
  sWb2[tid] = ldany(Wb2, tid, wf32);
  if (tid == 0) sba2 = ldany(ba2, 0, wf32);
  __syncthreads();
  if (tid >= 128 && tid < 192) {
    int ch = tid - 128;
    float sum = sp2[0][ch * 2] + sp2[1][ch * 2];
    float sq = sp2[0][ch * 2 + 1] + sp2[1][ch * 2 + 1];
    float mean = sum * (1.0f / 65536.0f);
    float var = sq * (1.0f / 65536.0f) - mean * mean;
    int o = ch & 31;
    float gg = ldany(ch < 32 ? g1 : g2, o, wf32);
    float be = ldany(ch < 32 ? be1 : be2, o, wf32);
    float scale = gg / sqrtf(var + 1e-5f);
    sstats[ch * 2] = scale;
    sstats[ch * 2 + 1] = be - mean * scale;
  }
  __syncthreads();

  float d0 = xvv[0] - pc3[0], d1 = xvv[1] - pc3[1], d2 = xvv[2] - pc3[2];
  float sq = d0 * d0 + d1 * d1 + d2 * d2;
  float temp = (sq > 0.0f) ? sqrtf(sq) : 0.0f;
  float pe[10] = {xvv[0], xvv[1], xvv[2], pc3[0], pc3[1], pc3[2], d0, d1, d2, temp};
  float feat[64];
#pragma unroll
  for (int o = 0; o < 32; ++o) {
    float acc = sbconv[o];
#pragma unroll
    for (int c = 0; c < 4; ++c) acc = fmaf(sWconv[o * 4 + c], xvv[c], acc);
    feat[o] = acc;
  }
#pragma unroll
  for (int o = 0; o < 32; ++o) {
    float acc = sbpos[o];
#pragma unroll
    for (int c = 0; c < 10; ++c) acc = fmaf(sWpos[o * 10 + c], pe[c], acc);
    feat[32 + o] = acc;
  }
#pragma unroll
  for (int c = 0; c < 64; ++c) {
    float v = fmaf(feat[c], sstats[c * 2], sstats[c * 2 + 1]);
    feat[c] = (v >= 0.f) ? v : 0.2f * v;
  }
  float att = sba2;
#pragma unroll 4
  for (int h = 0; h < 32; ++h) {
    float a0 = 0.f, a1 = 0.f, a2 = 0.f, a3 = 0.f;
#pragma unroll
    for (int c = 0; c < 64; c += 4) {
      a0 = fmaf(sWa1[h * 64 + c],     feat[c],     a0);
      a1 = fmaf(sWa1[h * 64 + c + 1], feat[c + 1], a1);
      a2 = fmaf(sWa1[h * 64 + c + 2], feat[c + 2], a2);
      a3 = fmaf(sWa1[h * 64 + c + 3], feat[c + 3], a3);
    }
    float acc = sba1[h] + ((a0 + a1) + (a2 + a3));
    acc = (acc >= 0.f) ? acc : 0.2f * acc;
    att = fmaf(sWa2[h], acc, att);
  }
  float mxv = att;
  for (int mk = 1; mk < 8; mk <<= 1) mxv = fmaxf(mxv, __shfl_xor(mxv, mk, 8));
  float e = expf(att - mxv);
  float se = e;
  for (int mk = 1; mk < 8; mk <<= 1) se += __shfl_xor(se, mk, 8);
  float a = e / se;
#pragma unroll
  for (int c = 0; c < 64; ++c) {
    float w = feat[c] * a;
    w += __shfl_xor(w, 1, 8);
    w += __shfl_xor(w, 2, 8);
    w += __shfl_xor(w, 4, 8);
    feat[c] = w;
  }
  int obase = b * 69 * S_;
#pragma unroll
  for (int oc = 0; oc < 8; ++oc) {
    int o = j * 8 + oc;
    float a0 = sbb1[o], a1 = 0.f, a2 = 0.f, a3 = 0.f;
#pragma unroll
    for (int c = 0; c < 64; c += 4) {
      a0 = fmaf(sWb1[o * 65 + c],     feat[c],     a0);
      a1 = fmaf(sWb1[o * 65 + c + 1], feat[c + 1], a1);
      a2 = fmaf(sWb1[o * 65 + c + 2], feat[c + 2], a2);
      a3 = fmaf(sWb1[o * 65 + c + 3], feat[c + 3], a3);
    }
    float acc = (a0 + a1) + (a2 + a3);
    float acc2 = sbb2[o];
    acc2 = fmaf(sWb2[o * 4 + 0], xc0, acc2);
    acc2 = fmaf(sWb2[o * 4 + 1], xc1, acc2);
    acc2 = fmaf(sWb2[o * 4 + 2], xc2, acc2);
    acc2 = fmaf(sWb2[o * 4 + 3], xc3, acc2);
    float r = acc + acc2;
    r = (r >= 0.f) ? r : 0.01f * r;
    int oi = obase + (5 + o) * S_ + i;
    if (xf32) ((float*)out)[oi] = r; else ((u16*)out)[oi] = f2bf(r);
  }
  if (j == 0) {
#pragma unroll
    for (int c = 0; c < 5; ++c) {
      int oi = obase + c * S_ + i;
      if (xf32) ((float*)out)[oi] = ((const float*)x)[xbase + c * P_ + p0];
      else      ((u16*)out)[oi]   = ((const u16*)x)[xbase + c * P_ + p0];
    }
  }
}

extern "C" void kernel_launch(void* const* d_in, const int* in_sizes, int n_in,
                              void* d_out, int out_size, void* d_ws, size_t ws_size,
                              hipStream_t stream) {
  const void* x     = d_in[0];
  const void* Wpos  = d_in[1];
  const void* bpos  = d_in[2];
  const void* g2    = d_in[3];
  const void* be2   = d_in[4];
  const void* Wconv = d_in[5];
  const void* bconv = d_in[6];
  const void* g1    = d_in[7];
  const void* be1   = d_in[8];
  const void* Wa1   = d_in[9];
  const void* ba1   = d_in[10];
  const void* Wa2   = d_in[11];
  const void* ba2   = d_in[12];
  const void* Wb1   = d_in[13];
  const void* bb1   = d_in[14];
  const void* Wb2   = d_in[15];
  const void* bb2   = d_in[16];
  (void)d_ws; (void)ws_size; (void)in_sizes; (void)n_in;

  hipLaunchKernelGGL(k_prep,    dim3(2),    dim3(256), 0, stream, x);
  hipLaunchKernelGGL(k_hist,    dim3(32),   dim3(256), 0, stream, x);
  hipLaunchKernelGGL(k_scan,    dim3(2),    dim3(256), 0, stream);
  hipLaunchKernelGGL(k_scatter, dim3(32),   dim3(256), 0, stream, x);
  hipLaunchKernelGGL(k_dt,      dim3(2),    dim3(256), 0, stream);
  hipLaunchKernelGGL(k_knn2,    dim3(2048), dim3(256), 0, stream, x);
  hipLaunchKernelGGL(k_tail,    dim3(256),  dim3(256), 0, stream, x,
                     Wpos, bpos, Wconv, bconv);
  hipLaunchKernelGGL(k_pass2,   dim3(256),  dim3(256), 0, stream, x,
                     Wpos, bpos, Wconv, bconv, g1, be1, g2, be2,
                     Wa1, ba1, Wa2, ba2, Wb1, bb1, Wb2, bb2, d_out);
}

// Round 9
// 325.169 us; speedup vs baseline: 1.9174x; 1.1273x over previous
//
#include <hip/hip_runtime.h>
#include <math.h>

#define B_ 2
#define P_ 16384
#define C_ 5
#define S_ 4096
#define KNN_ 8
#define L_ 64

typedef unsigned short u16;
typedef unsigned int u32;
typedef unsigned long long u64;

// ---- static scratch: fully rewritten every call before any read ----
__device__ int    g_idxk[B_ * KNN_ * S_];
__device__ float  g_partials[256 * 128];   // [tail_block][slot], wave-coalesced
__device__ float  g_mnmx[B_][5];           // mn0,mx0,mn1,mx1,amax^2
__device__ int    g_hist[B_ * 4097];       // bin starts after scan (+sentinel)
__device__ int    g_cursor[B_ * 4096];     // scatter cursors
__device__ int    g_binof[B_ * P_];        // bin of each point
__device__ int    g_dt[B_ * 4096];         // Chebyshev dist to nearest occupied bin
__device__ u64    g_mask[B_ * 64];         // row occupancy bitmasks
__device__ float4 g_recA[B_ * P_];         // (v0, v1, xx2d, idx_bits)
__device__ float4 g_recB[B_ * P_];         // (v0, v1, v2, xx3)
__device__ u16    g_idxsc[B_ * P_];        // original idx per scattered record

__device__ __forceinline__ float bf2f(u16 u) {
  union { u32 i; float f; } c; c.i = ((u32)u) << 16; return c.f;
}
__device__ __forceinline__ u16 f2bf(float f) {
  union { float f; u32 i; } c; c.f = f;
  u32 r = c.i + 0x7fffu + ((c.i >> 16) & 1u);
  return (u16)(r >> 16);
}
__device__ __forceinline__ float ldany(const void* p, int i, int f32) {
  return f32 ? ((const float*)p)[i] : bf2f(((const u16*)p)[i]);
}

// ---- (d, idx) -> fixed-exponent positive double; order == (d desc, idx asc); unique ----
__device__ __forceinline__ double packkey(float d, int idx) {
  u32 bits = __float_as_uint(d);
  u32 key = bits ^ ((u32)(((int)bits) >> 31) | 0x80000000u);  // monotone u32 map of f32
  int hi = (int)(0x3FF00000u | (key >> 12));
  int lo = (int)((key << 20) | ((u32)(16383 - idx) << 6));
  return __hiloint2double(hi, lo);
}
__device__ __forceinline__ int keyidx(double w) {
  return 16383 - (int)(((u32)__double2loint(w) >> 6) & 16383u);
}
// inverse of the monotone map: recover the float d stored in a key
__device__ __forceinline__ float keyd(double w) {
  u32 hi = (u32)__double2hiint(w), lo = (u32)__double2loint(w);
  u32 key = (hi << 12) | (lo >> 20);
  u32 mask = (u32)(((int)key) >> 31);
  u32 bits = key ^ ((~mask) | 0x80000000u);
  return __uint_as_float(bits);
}

__device__ __forceinline__ int chk_bad(const void* p, int n, int tid, int stride) {
  int bad = 0;
  for (int i = tid; i < n; i += stride) {
    float f = bf2f(((const u16*)p)[i]);
    if (!(f == f) || fabsf(f) > 1024.0f) bad = 1;
  }
  return bad;
}

__device__ __forceinline__ void cmpswap(double& a, double& b) {
  double hi = fmax(a, b), lo = fmin(a, b);
  a = hi; b = lo;
}

// named-register sorted-desc top-8 insert
#define INS8(key)                                                        \
  do {                                                                   \
    if ((key) > a7) {                                                    \
      double t_ = (key), h_;                                             \
      h_ = fmax(a0, t_); t_ = fmin(a0, t_); a0 = h_;                     \
      h_ = fmax(a1, t_); t_ = fmin(a1, t_); a1 = h_;                     \
      h_ = fmax(a2, t_); t_ = fmin(a2, t_); a2 = h_;                     \
      h_ = fmax(a3, t_); t_ = fmin(a3, t_); a3 = h_;                     \
      h_ = fmax(a4, t_); t_ = fmin(a4, t_); a4 = h_;                     \
      h_ = fmax(a5, t_); t_ = fmin(a5, t_); a5 = h_;                     \
      h_ = fmax(a6, t_); t_ = fmin(a6, t_); a6 = h_;                     \
      a7 = fmax(a7, t_);                                                 \
    }                                                                    \
  } while (0)

#define MAX64(w)                                                         \
  do {                                                                   \
    w = fmax(w, __shfl_xor(w, 1, 64));                                   \
    w = fmax(w, __shfl_xor(w, 2, 64));                                   \
    w = fmax(w, __shfl_xor(w, 4, 64));                                   \
    w = fmax(w, __shfl_xor(w, 8, 64));                                   \
    w = fmax(w, __shfl_xor(w, 16, 64));                                  \
    w = fmax(w, __shfl_xor(w, 32, 64));                                  \
  } while (0)

// 64-lane butterfly: merge per-lane sorted-desc 8-lists into the exact union
// top-8 (sorted desc, identical in all lanes). Per stage: bitonic-split max
// (n_k = max(v_k, u_{7-k})) + 3-layer bitonic cleanup. Lists must be
// pairwise-disjoint candidate sets (each candidate in exactly one lane).
#define BMERGE8(v0, v1, v2, v3, v4, v5, v6, v7)                          \
  do {                                                                   \
    for (int m_ = 1; m_ < 64; m_ <<= 1) {                                \
      double u0_ = __shfl_xor(v0, m_, 64), u1_ = __shfl_xor(v1, m_, 64); \
      double u2_ = __shfl_xor(v2, m_, 64), u3_ = __shfl_xor(v3, m_, 64); \
      double u4_ = __shfl_xor(v4, m_, 64), u5_ = __shfl_xor(v5, m_, 64); \
      double u6_ = __shfl_xor(v6, m_, 64), u7_ = __shfl_xor(v7, m_, 64); \
      v0 = fmax(v0, u7_); v1 = fmax(v1, u6_);                            \
      v2 = fmax(v2, u5_); v3 = fmax(v3, u4_);                            \
      v4 = fmax(v4, u3_); v5 = fmax(v5, u2_);                            \
      v6 = fmax(v6, u1_); v7 = fmax(v7, u0_);                            \
      cmpswap(v0, v4); cmpswap(v1, v5); cmpswap(v2, v6); cmpswap(v3, v7);\
      cmpswap(v0, v2); cmpswap(v1, v3); cmpswap(v4, v6); cmpswap(v5, v7);\
      cmpswap(v0, v1); cmpswap(v2, v3); cmpswap(v4, v5); cmpswap(v6, v7);\
    }                                                                    \
  } while (0)

// ring cell enumeration (Chebyshev ring R, t-th cell of 8R)
__device__ __forceinline__ void ringcell(int R, int t, int cx, int cy, int& X, int& Y) {
  int side = 2 * R + 1;
  if (t < side)          { X = cx - R + t;          Y = cy - R; }
  else if (t < 2 * side) { X = cx - R + (t - side); Y = cy + R; }
  else {
    int u = t - 2 * side, m2 = 2 * R - 1;
    if (u < m2) { X = cx - R; Y = cy - R + 1 + u; }
    else        { X = cx + R; Y = cy - R + 1 + (u - m2); }
  }
}

// ---------------- prep: min/max + |max| bound, zero histogram (1024 thr) ----------------
__global__ __launch_bounds__(1024) void k_prep(const void* __restrict__ xv) {
  __shared__ int sbad;
  __shared__ float sred[16][5];
  int tid = threadIdx.x, b = blockIdx.x;
  if (tid == 0) sbad = 0;
  __syncthreads();
  if (chk_bad(xv, 1024, tid, 1024)) atomicOr(&sbad, 1);
  __syncthreads();
  const int f32 = sbad;
  int base0 = b * C_ * P_, base1 = base0 + P_, base2 = base1 + P_;
  float mn0 = INFINITY, mx0 = -INFINITY, mn1 = INFINITY, mx1 = -INFINITY, am = 0.f;
  for (int p = tid; p < P_; p += 1024) {
    float v0 = ldany(xv, base0 + p, f32);
    float v1 = ldany(xv, base1 + p, f32);
    float v2 = ldany(xv, base2 + p, f32);
    mn0 = fminf(mn0, v0); mx0 = fmaxf(mx0, v0);
    mn1 = fminf(mn1, v1); mx1 = fmaxf(mx1, v1);
    am = fmaxf(am, fabsf(v2));
  }
  for (int off = 32; off; off >>= 1) {
    mn0 = fminf(mn0, __shfl_down(mn0, off)); mx0 = fmaxf(mx0, __shfl_down(mx0, off));
    mn1 = fminf(mn1, __shfl_down(mn1, off)); mx1 = fmaxf(mx1, __shfl_down(mx1, off));
    am = fmaxf(am, __shfl_down(am, off));
  }
  int l = tid & 63, g = tid >> 6;
  if (l == 0) {
    sred[g][0] = mn0; sred[g][1] = mx0; sred[g][2] = mn1; sred[g][3] = mx1; sred[g][4] = am;
  }
  __syncthreads();
  if (tid == 0) {
    float a0 = sred[0][0], a1 = sred[0][1], a2 = sred[0][2], a3 = sred[0][3], a4 = sred[0][4];
    for (int w = 1; w < 16; ++w) {
      a0 = fminf(a0, sred[w][0]); a1 = fmaxf(a1, sred[w][1]);
      a2 = fminf(a2, sred[w][2]); a3 = fmaxf(a3, sred[w][3]);
      a4 = fmaxf(a4, sred[w][4]);
    }
    float aa = fmaxf(fmaxf(fabsf(a0), fabsf(a1)), fmaxf(fmaxf(fabsf(a2), fabsf(a3)), a4));
    g_mnmx[b][0] = a0; g_mnmx[b][1] = a1; g_mnmx[b][2] = a2; g_mnmx[b][3] = a3;
    g_mnmx[b][4] = aa * aa;
  }
  for (int i2 = tid; i2 < 4097; i2 += 1024) g_hist[b * 4097 + i2] = 0;
}

// ---------------- histogram + per-point bin ----------------
__global__ __launch_bounds__(256) void k_hist(const void* __restrict__ xv) {
  __shared__ int sbad;
  int tid = threadIdx.x, blk = blockIdx.x;
  if (tid == 0) sbad = 0;
  __syncthreads();
  if (chk_bad(xv, 1024, tid, 256)) atomicOr(&sbad, 1);
  __syncthreads();
  const int f32 = sbad;
  int b = blk >> 4;
  int pb = (blk & 15) * 1024;
  int base0 = b * C_ * P_, base1 = base0 + P_;
  float mn0 = g_mnmx[b][0], mx0 = g_mnmx[b][1], mn1 = g_mnmx[b][2], mx1 = g_mnmx[b][3];
  float r0 = __fsub_rn(mx0, mn0), r1 = __fsub_rn(mx1, mn1);
  float inv0 = (r0 > 0.f) ? 64.0f / r0 : 0.f;
  float inv1 = (r1 > 0.f) ? 64.0f / r1 : 0.f;
  for (int q = 0; q < 4; ++q) {
    int i = pb + q * 256 + tid;
    float v0 = ldany(xv, base0 + i, f32);
    float v1 = ldany(xv, base1 + i, f32);
    int bx = (int)fminf(fmaxf((v0 - mn0) * inv0, 0.f), 63.f);
    int by = (int)fminf(fmaxf((v1 - mn1) * inv1, 0.f), 63.f);
    int bin = by * 64 + bx;
    g_binof[b * P_ + i] = bin;
    atomicAdd(&g_hist[b * 4097 + bin], 1);
  }
}

// ---------------- fused: exclusive prefix + occupancy masks + distance transform ----------------
__global__ __launch_bounds__(256) void k_scan_dt() {
  __shared__ int part[256];
  __shared__ u32 occw[128];
  __shared__ short rowd[64][64];
  int b = blockIdx.x, t = threadIdx.x;
  if (t < 128) occw[t] = 0;
  __syncthreads();
  int loc[16]; int s0 = 0;
  u32 bits16 = 0;
  for (int q = 0; q < 16; ++q) {
    loc[q] = g_hist[b * 4097 + t * 16 + q];
    s0 += loc[q];
    if (loc[q] > 0) bits16 |= (1u << q);
  }
  part[t] = s0;
  atomicOr(&occw[t >> 1], bits16 << ((t & 1) * 16));
  __syncthreads();
  for (int d2 = 1; d2 < 256; d2 <<= 1) {
    int v = (t >= d2) ? part[t - d2] : 0;
    __syncthreads();
    part[t] += v;
    __syncthreads();
  }
  int run = (t == 0) ? 0 : part[t - 1];
  for (int q = 0; q < 16; ++q) {
    g_hist[b * 4097 + t * 16 + q] = run;
    g_cursor[b * 4096 + t * 16 + q] = run;
    run += loc[q];
  }
  if (t == 0) g_hist[b * 4097 + 4096] = P_;
  if (t < 64) {
    u64 m = ((u64)occw[2 * t + 1] << 32) | (u64)occw[2 * t];
    g_mask[b * 64 + t] = m;
  }
#pragma unroll
  for (int q = 0; q < 16; ++q) {            // rowdist for 16 cells per thread
    int c = q * 256 + t, y = c >> 6, x = c & 63;
    u64 m = ((u64)occw[2 * y + 1] << 32) | (u64)occw[2 * y];
    int rd = 127;
    if (m) {
      u64 hi = m >> x;
      int dhi = hi ? (__ffsll((long long)hi) - 1) : 127;
      u64 lo = (x < 63) ? (m & (((u64)1 << (x + 1)) - 1)) : m;
      int dlo = lo ? (x - (63 - __clzll((long long)lo))) : 127;
      rd = min(dhi, dlo);
    }
    rowd[y][x] = (short)rd;
  }
  __syncthreads();
#pragma unroll
  for (int q = 0; q < 16; ++q) {            // column fold: dt = min_y' max(|dy|, rowd)
    int c = q * 256 + t, y = c >> 6, x = c & 63;
    int best = 127;
    for (int dy = 0; dy < 64; ++dy) {
      if (dy >= best) break;
      int y1 = y - dy, y2 = y + dy;
      if (y1 >= 0) { int v = rowd[y1][x]; best = min(best, (dy > v) ? dy : v); }
      if (dy && y2 < 64) { int v = rowd[y2][x]; best = min(best, (dy > v) ? dy : v); }
    }
    g_dt[(b << 12) + c] = best;
  }
}

// ---------------- scatter points into binned records ----------------
__global__ __launch_bounds__(256) void k_scatter(const void* __restrict__ xv) {
  __shared__ int sbad;
  int tid = threadIdx.x, blk = blockIdx.x;
  if (tid == 0) sbad = 0;
  __syncthreads();
  if (chk_bad(xv, 1024, tid, 256)) atomicOr(&sbad, 1);
  __syncthreads();
  const int f32 = sbad;
  int b = blk >> 4;
  int pb = (blk & 15) * 1024;
  int base0 = b * C_ * P_, base1 = base0 + P_, base2 = base1 + P_;
  for (int q = 0; q < 4; ++q) {
    int i = pb + q * 256 + tid;
    float a0 = ldany(xv, base0 + i, f32);
    float a1 = ldany(xv, base1 + i, f32);
    float a2 = ldany(xv, base2 + i, f32);
    // EXACT expression trees matching the verified brute-force staging:
    float xx2d = __fadd_rn(__fmul_rn(a0, a0), __fmul_rn(a1, a1));
    float xx3  = __fadd_rn(__fadd_rn(__fmul_rn(a0, a0), __fmul_rn(a1, a1)), __fmul_rn(a2, a2));
    int bin = g_binof[b * P_ + i];
    int pos = atomicAdd(&g_cursor[b * 4096 + bin], 1);
    g_recA[(b << 14) + pos] = make_float4(a0, a1, xx2d, __int_as_float(i));
    g_recB[(b << 14) + pos] = make_float4(a0, a1, a2, xx3);
    g_idxsc[(b << 14) + pos] = (u16)i;
  }
}

// ---------------- binned exact kNN: one 64-lane wave per query ----------------
// Bounds and final answer via 6-stage bitonic top-8 merge (exact union top-8,
// sorted, broadcast) computed on register copies; per-lane lists stay disjoint.
__global__ __launch_bounds__(256) void k_knn2(const void* __restrict__ xv) {
  __shared__ int shist[4097];
  __shared__ u64 smask[64];
  __shared__ int sbad;
  int tid = threadIdx.x;
  if (tid == 0) sbad = 0;
  __syncthreads();
  if (chk_bad(xv, 1024, tid, 256)) atomicOr(&sbad, 1);
  __syncthreads();
  const int f32 = sbad;

  int blk = blockIdx.x;
  int b = blk >> 10;                         // 1024 blocks per batch element
  int bb = blk & 1023;
  for (int i2 = tid; i2 < 4097; i2 += 256) shist[i2] = g_hist[b * 4097 + i2];
  if (tid < 64) smask[tid] = g_mask[b * 64 + tid];   // coalesced, conflict-free
  __syncthreads();

  int l = tid & 63;                          // lane within the query's wave
  int grp = l >> 3, lo = l & 7;
  int s = (tid >> 6) * 1024 + bb;            // interleaved query id: balances blocks
  int base0 = b * C_ * P_, base1 = base0 + P_, base2 = base1 + P_;

  float mn0 = g_mnmx[b][0], mx0 = g_mnmx[b][1], mn1 = g_mnmx[b][2], mx1 = g_mnmx[b][3];
  float margin = 2e-5f * g_mnmx[b][4];
  float r0 = __fsub_rn(mx0, mn0), r1 = __fsub_rn(mx1, mn1);
  float w0 = r0 * 0.015625f, w1 = r1 * 0.015625f;
  float wmin = fminf(w0, w1) * 0.999f;       // conservative slack vs fp rounding
  const float4* recA = g_recA + (b << 14);
  const float4* recB = g_recB + (b << 14);

  // ---- phase A: nearest (2D) to lattice node s ----
  float mm0 = (float)(s & (L_ - 1)) * 0.015625f;
  float mm1 = (float)(s >> 6) * 0.015625f;
  float ps0 = __fadd_rn(__fmul_rn(mm0, r0), mn0);
  float ps1 = __fadd_rn(__fmul_rn(mm1, r1), mn1);
  float xx2q = __fadd_rn(__fmul_rn(ps0, ps0), __fmul_rn(ps1, ps1));
  int bqx = s & 63, bqy = s >> 6;            // exact bin identity
  int R0 = g_dt[(b << 12) + s];              // rings < R0 provably empty
  double bestA = -1.0;
  if (R0 <= 1) {                             // 3x3 core: all 64 lanes split records
#pragma unroll
    for (int dy = -1; dy <= 1; ++dy) {
#pragma unroll
      for (int dx = -1; dx <= 1; ++dx) {
        int X = bqx + dx, Y = bqy + dy;
        if ((unsigned)X > 63u || (unsigned)Y > 63u) continue;
        if (!((smask[Y] >> X) & 1ull)) continue;
        int bin = Y * 64 + X;
        int st = shist[bin], en = shist[bin + 1];
        for (int j2 = st + l; j2 < en; j2 += 64) {
          float4 rc = recA[j2];
          float dot = __fadd_rn(__fmul_rn(rc.x, ps0), __fmul_rn(rc.y, ps1));
          float inner = __fmul_rn(-2.0f, dot);
          float d = __fsub_rn(__fsub_rn(-rc.z, inner), xx2q);
          bestA = fmax(bestA, packkey(d, __float_as_int(rc.w)));
        }
      }
    }
  }
  double t1 = bestA;                         // exact union best (broadcast)
  MAX64(t1);
  for (int R = (R0 < 2 ? 2 : R0); R < 64; ++R) {
    if (t1 >= 1.0) {
      float lb = (float)(R - 1) * wmin;
      float ub = __fadd_rn(-(lb * lb), margin);
      if (ub < keyd(t1)) break;
    }
    int cnt = 8 * R;
    for (int t = grp; t < cnt; t += 8) {
      int X, Y;
      ringcell(R, t, bqx, bqy, X, Y);
      if ((unsigned)X > 63u || (unsigned)Y > 63u) continue;
      if (!((smask[Y] >> X) & 1ull)) continue;
      int bin = Y * 64 + X;
      int st = shist[bin], en = shist[bin + 1];
      for (int j2 = st + lo; j2 < en; j2 += 8) {
        float4 rc = recA[j2];
        float dot = __fadd_rn(__fmul_rn(rc.x, ps0), __fmul_rn(rc.y, ps1));
        float inner = __fmul_rn(-2.0f, dot);
        float d = __fsub_rn(__fsub_rn(-rc.z, inner), xx2q);
        bestA = fmax(bestA, packkey(d, __float_as_int(rc.w)));
      }
    }
    if (__any(bestA > t1)) { t1 = bestA; MAX64(t1); }   // lazy exact refresh
  }
  int qi = keyidx(t1) & (P_ - 1);

  // ---- phase B: top-8 (3D) from data point qi (its bin occupied) ----
  float q0 = ldany(xv, base0 + qi, f32);
  float q1 = ldany(xv, base1 + qi, f32);
  float q2 = ldany(xv, base2 + qi, f32);
  float xx3q = __fadd_rn(__fadd_rn(__fmul_rn(q0, q0), __fmul_rn(q1, q1)), __fmul_rn(q2, q2));
  int qbin = g_binof[b * P_ + qi];
  int cx = qbin & 63, cy = qbin >> 6;
  double a0 = -1.0, a1 = -1.0, a2 = -1.0, a3 = -1.0,
         a4 = -1.0, a5 = -1.0, a6 = -1.0, a7 = -1.0;
#pragma unroll
  for (int dy = -1; dy <= 1; ++dy) {         // 3x3 core: 64-lane record split
#pragma unroll
    for (int dx = -1; dx <= 1; ++dx) {
      int X = cx + dx, Y = cy + dy;
      if ((unsigned)X > 63u || (unsigned)Y > 63u) continue;
      if (!((smask[Y] >> X) & 1ull)) continue;
      int bin = Y * 64 + X;
      int st = shist[bin], en = shist[bin + 1];
      for (int j2 = st + l; j2 < en; j2 += 64) {
        float4 rc = recB[j2];
        int idx = (int)g_idxsc[(b << 14) + j2];
        float dot = __fadd_rn(__fadd_rn(__fmul_rn(rc.x, q0), __fmul_rn(rc.y, q1)),
                              __fmul_rn(rc.z, q2));
        float inner = __fmul_rn(-2.0f, dot);
        float d = __fsub_rn(__fsub_rn(-rc.w, inner), xx3q);
        double key = packkey(d, idx);
        INS8(key);
      }
    }
  }
  // exact union top-8 via bitonic merge on copies (sorted desc, all lanes)
  double m0 = a0, m1 = a1, m2 = a2, m3 = a3, m4 = a4, m5 = a5, m6 = a6, m7 = a7;
  BMERGE8(m0, m1, m2, m3, m4, m5, m6, m7);
  double t8 = m7;
  for (int R = 2; R < 64; ++R) {
    if (t8 >= 1.0) {
      float lb = (float)(R - 1) * wmin;      // 2D lower bound of 3D distance
      float ub = __fadd_rn(-(lb * lb), margin);
      if (ub < keyd(t8)) break;
    }
    bool added = false;
    int cnt = 8 * R;
    for (int t = grp; t < cnt; t += 8) {
      int X, Y;
      ringcell(R, t, cx, cy, X, Y);
      if ((unsigned)X > 63u || (unsigned)Y > 63u) continue;
      if (!((smask[Y] >> X) & 1ull)) continue;
      int bin = Y * 64 + X;
      int st = shist[bin], en = shist[bin + 1];
      for (int j2 = st + lo; j2 < en; j2 += 8) {
        float4 rc = recB[j2];
        int idx = (int)g_idxsc[(b << 14) + j2];
        float dot = __fadd_rn(__fadd_rn(__fmul_rn(rc.x, q0), __fmul_rn(rc.y, q1)),
                              __fmul_rn(rc.z, q2));
        float inner = __fmul_rn(-2.0f, dot);
        float d = __fsub_rn(__fsub_rn(-rc.w, inner), xx3q);
        double key = packkey(d, idx);
        added = added || (key > t8);
        INS8(key);
      }
    }
    if (__any(added)) {                      // lazy refresh: remerge copies
      m0 = a0; m1 = a1; m2 = a2; m3 = a3; m4 = a4; m5 = a5; m6 = a6; m7 = a7;
      BMERGE8(m0, m1, m2, m3, m4, m5, m6, m7);
      t8 = m7;
    }
  }
  // merged list IS the answer: lane l takes rank l (lists identical in all lanes)
  double wk = m7;
  if (l == 0) wk = m0; else if (l == 1) wk = m1; else if (l == 2) wk = m2;
  else if (l == 3) wk = m3; else if (l == 4) wk = m4; else if (l == 5) wk = m5;
  else if (l == 6) wk = m6;
  if (l < 8) g_idxk[b * 32768 + l * 4096 + s] = keyidx(wk);   // rank-major (B,k,s)
}

// ---------------- BN partial sums (decoupled tail) ----------------
__global__ __launch_bounds__(256) void k_tail(const void* __restrict__ x,
                                              const void* __restrict__ Wpos,
                                              const void* __restrict__ bpos,
                                              const void* __restrict__ Wconv,
                                              const void* __restrict__ bconv) {
  __shared__ float sWpos[320], sbpos[32], sWconv[128], sbconv[32];
  __shared__ float sacc[16][128];
  __shared__ int sbx, sbw;
  int tid = threadIdx.x;
  if (tid == 0) { sbx = 0; sbw = 0; }
  __syncthreads();
  if (chk_bad(x, 1024, tid, 256)) atomicOr(&sbx, 1);
  if (chk_bad(Wpos, 320, tid, 256) | chk_bad(Wconv, 128, tid, 256)) atomicOr(&sbw, 1);
  __syncthreads();
  const int f32 = sbx, wf32 = sbw;

  int id = blockIdx.x * 256 + tid;          // element in [0, 65536)
  int b = id >> 15, n = id & 32767;
  const int* fb = g_idxk + b * 32768;
  int base0 = b * C_ * P_;
  int p = fb[n] & (P_ - 1);
  int p0 = fb[n & ~7] & (P_ - 1);
  float xvv[4], pc3[3];
#pragma unroll
  for (int cc = 0; cc < 4; ++cc) xvv[cc] = ldany(x, base0 + cc * P_ + p, f32);
#pragma unroll
  for (int cc = 0; cc < 3; ++cc) pc3[cc] = ldany(x, base0 + cc * P_ + p0, f32);

  for (int i2 = tid; i2 < 320; i2 += 256) sWpos[i2] = ldany(Wpos, i2, wf32);
  if (tid < 128) sWconv[tid] = ldany(Wconv, tid, wf32);
  if (tid < 32) { sbpos[tid] = ldany(bpos, tid, wf32); sbconv[tid] = ldany(bconv, tid, wf32); }
  __syncthreads();

  float d0 = xvv[0] - pc3[0], d1 = xvv[1] - pc3[1], d2 = xvv[2] - pc3[2];
  float sq = d0 * d0 + d1 * d1 + d2 * d2;
  float temp = (sq > 0.0f) ? sqrtf(sq) : 0.0f;
  float pe[10] = {xvv[0], xvv[1], xvv[2], pc3[0], pc3[1], pc3[2], d0, d1, d2, temp};
#pragma unroll
  for (int o = 0; o < 64; ++o) {
    float v;
    if (o < 32) {
      v = sbconv[o];
#pragma unroll
      for (int cc = 0; cc < 4; ++cc) v = fmaf(sWconv[o * 4 + cc], xvv[cc], v);
    } else {
      v = sbpos[o - 32];
#pragma unroll
      for (int cc = 0; cc < 10; ++cc) v = fmaf(sWpos[(o - 32) * 10 + cc], pe[cc], v);
    }
    float sv = v, qv = v * v;
    for (int m = 1; m < 16; m <<= 1) { sv += __shfl_xor(sv, m, 16); qv += __shfl_xor(qv, m, 16); }
    if ((tid & 15) == 0) { sacc[tid >> 4][o * 2] = sv; sacc[tid >> 4][o * 2 + 1] = qv; }
  }
  __syncthreads();
  if (tid < 128) {
    float a = 0.f;
#pragma unroll
    for (int w = 0; w < 16; ++w) a += sacc[w][tid];
    g_partials[blockIdx.x * 128 + tid] = a;
  }
}

// ---------------- pass 2 : BN stats + recompute + attention + output ----------------
__global__ __launch_bounds__(256) void k_pass2(const void* __restrict__ x,
                                               const void* __restrict__ Wpos,
                                               const void* __restrict__ bpos,
                                               const void* __restrict__ Wconv,
                                               const void* __restrict__ bconv,
                                               const void* __restrict__ g1,
                                               const void* __restrict__ be1,
                                               const void* __restrict__ g2,
                                               const void* __restrict__ be2,
                                               const void* __restrict__ Wa1,
                                               const void* __restrict__ ba1,
                                               const void* __restrict__ Wa2,
                                               const void* __restrict__ ba2,
                                               const void* __restrict__ Wb1,
                                               const void* __restrict__ bb1,
                                               const void* __restrict__ Wb2,
                                               const void* __restrict__ bb2,
                                               void* __restrict__ out) {
  __shared__ float sWpos[320], sbpos[32], sWconv[128], sbconv[32];
  __shared__ float sWa1[2048], sba1[32], sWa2[32];
  __shared__ float sWb1[64 * 65];
  __shared__ float sbb1[64], sWb2[256], sbb2[64], sstats[128];
  __shared__ float sp2[2][128];
  __shared__ float sba2;
  __shared__ int sbx, sbw;
  int tid = threadIdx.x;
  if (tid == 0) { sbx = 0; sbw = 0; }
  __syncthreads();
  if (chk_bad(x, 1024, tid, 256)) atomicOr(&sbx, 1);
  if (chk_bad(Wa1, 2048, tid, 256) | chk_bad(Wb1, 4096, tid, 256)) atomicOr(&sbw, 1);
  __syncthreads();
  int xf32 = sbx, wf32 = sbw;

  int g = blockIdx.x * 32 + (tid >> 3);
  int j = tid & 7;
  int b = g >> 12, i = g & (S_ - 1);
  int n = i * 8 + j;
  const int* fb = g_idxk + b * 32768;
  int xbase = b * C_ * P_;
  int p = fb[n] & (P_ - 1);
  int p0 = fb[n & ~7] & (P_ - 1);
  float xvv[4];
#pragma unroll
  for (int c = 0; c < 4; ++c) xvv[c] = ldany(x, xbase + c * P_ + p, xf32);
  float pc3[3];
#pragma unroll
  for (int c = 0; c < 3; ++c) pc3[c] = ldany(x, xbase + c * P_ + p0, xf32);
  float xc0 = ldany(x, xbase + p0, xf32);
  float xc1 = ldany(x, xbase + P_ + p0, xf32);
  float xc2 = ldany(x, xbase + 2 * P_ + p0, xf32);
  float xc3 = ldany(x, xbase + 3 * P_ + p0, xf32);

  {
    int slot = tid & 127, half = tid >> 7;
    float a0 = 0.f, a1 = 0.f;
    for (int blk = half * 128; blk < half * 128 + 128; blk += 2) {
      a0 += g_partials[blk * 128 + slot];
      a1 += g_partials[(blk + 1) * 128 + slot];
    }
    sp2[half][slot] = a0 + a1;
  }
  for (int i2 = tid; i2 < 320; i2 += 256) sWpos[i2] = ldany(Wpos, i2, wf32);
  if (tid < 128) sWconv[tid] = ldany(Wconv, tid, wf32);
  if (tid < 32) { sbpos[tid] = ldany(bpos, tid, wf32); sbconv[tid] = ldany(bconv, tid, wf32); }
  for (int i2 = tid; i2 < 2048; i2 += 256) sWa1[i2] = ldany(Wa1, i2, wf32);
  for (int i2 = tid; i2 < 4096; i2 += 256) sWb1[(i2 >> 6) * 65 + (i2 & 63)] = ldany(Wb1, i2, wf32);
  if (tid >= 32 && tid < 64) { sba1[tid - 32] = ldany(ba1, tid - 32, wf32); sWa2[tid - 32] = ldany(Wa2, tid - 32, wf32); }
  if (tid >= 64 && tid < 128) { sbb1[tid - 64] = ldany(bb1, tid - 64, wf32); sbb2[tid - 64] = ldany(bb2, tid - 64, wf32); }
  sWb2[tid] = ldany(Wb2, tid, wf32);
  if (tid == 0) sba2 = ldany(ba2, 0, wf32);
  __syncthreads();
  if (tid >= 128 && tid < 192) {
    int ch = tid - 128;
    float sum = sp2[0][ch * 2] + sp2[1][ch * 2];
    float sq = sp2[0][ch * 2 + 1] + sp2[1][ch * 2 + 1];
    float mean = sum * (1.0f / 65536.0f);
    float var = sq * (1.0f / 65536.0f) - mean * mean;
    int o = ch & 31;
    float gg = ldany(ch < 32 ? g1 : g2, o, wf32);
    float be = ldany(ch < 32 ? be1 : be2, o, wf32);
    float scale = gg / sqrtf(var + 1e-5f);
    sstats[ch * 2] = scale;
    sstats[ch * 2 + 1] = be - mean * scale;
  }
  __syncthreads();

  float d0 = xvv[0] - pc3[0], d1 = xvv[1] - pc3[1], d2 = xvv[2] - pc3[2];
  float sq = d0 * d0 + d1 * d1 + d2 * d2;
  float temp = (sq > 0.0f) ? sqrtf(sq) : 0.0f;
  float pe[10] = {xvv[0], xvv[1], xvv[2], pc3[0], pc3[1], pc3[2], d0, d1, d2, temp};
  float feat[64];
#pragma unroll
  for (int o = 0; o < 32; ++o) {
    float acc = sbconv[o];
#pragma unroll
    for (int c = 0; c < 4; ++c) acc = fmaf(sWconv[o * 4 + c], xvv[c], acc);
    feat[o] = acc;
  }
#pragma unroll
  for (int o = 0; o < 32; ++o) {
    float acc = sbpos[o];
#pragma unroll
    for (int c = 0; c < 10; ++c) acc = fmaf(sWpos[o * 10 + c], pe[c], acc);
    feat[32 + o] = acc;
  }
#pragma unroll
  for (int c = 0; c < 64; ++c) {
    float v = fmaf(feat[c], sstats[c * 2], sstats[c * 2 + 1]);
    feat[c] = (v >= 0.f) ? v : 0.2f * v;
  }
  float att = sba2;
#pragma unroll 4
  for (int h = 0; h < 32; ++h) {
    float a0 = 0.f, a1 = 0.f, a2 = 0.f, a3 = 0.f;
#pragma unroll
    for (int c = 0; c < 64; c += 4) {
      a0 = fmaf(sWa1[h * 64 + c],     feat[c],     a0);
      a1 = fmaf(sWa1[h * 64 + c + 1], feat[c + 1], a1);
      a2 = fmaf(sWa1[h * 64 + c + 2], feat[c + 2], a2);
      a3 = fmaf(sWa1[h * 64 + c + 3], feat[c + 3], a3);
    }
    float acc = sba1[h] + ((a0 + a1) + (a2 + a3));
    acc = (acc >= 0.f) ? acc : 0.2f * acc;
    att = fmaf(sWa2[h], acc, att);
  }
  float mxv = att;
  for (int mk = 1; mk < 8; mk <<= 1) mxv = fmaxf(mxv, __shfl_xor(mxv, mk, 8));
  float e = expf(att - mxv);
  float se = e;
  for (int mk = 1; mk < 8; mk <<= 1) se += __shfl_xor(se, mk, 8);
  float a = e / se;
#pragma unroll
  for (int c = 0; c < 64; ++c) {
    float w = feat[c] * a;
    w += __shfl_xor(w, 1, 8);
    w += __shfl_xor(w, 2, 8);
    w += __shfl_xor(w, 4, 8);
    feat[c] = w;
  }
  int obase = b * 69 * S_;
#pragma unroll
  for (int oc = 0; oc < 8; ++oc) {
    int o = j * 8 + oc;
    float a0 = sbb1[o], a1 = 0.f, a2 = 0.f, a3 = 0.f;
#pragma unroll
    for (int c = 0; c < 64; c += 4) {
      a0 = fmaf(sWb1[o * 65 + c],     feat[c],     a0);
      a1 = fmaf(sWb1[o * 65 + c + 1], feat[c + 1], a1);
      a2 = fmaf(sWb1[o * 65 + c + 2], feat[c + 2], a2);
      a3 = fmaf(sWb1[o * 65 + c + 3], feat[c + 3], a3);
    }
    float acc = (a0 + a1) + (a2 + a3);
    float acc2 = sbb2[o];
    acc2 = fmaf(sWb2[o * 4 + 0], xc0, acc2);
    acc2 = fmaf(sWb2[o * 4 + 1], xc1, acc2);
    acc2 = fmaf(sWb2[o * 4 + 2], xc2, acc2);
    acc2 = fmaf(sWb2[o * 4 + 3], xc3, acc2);
    float r = acc + acc2;
    r = (r >= 0.f) ? r : 0.01f * r;
    int oi = obase + (5 + o) * S_ + i;
    if (xf32) ((float*)out)[oi] = r; else ((u16*)out)[oi] = f2bf(r);
  }
  if (j == 0) {
#pragma unroll
    for (int c = 0; c < 5; ++c) {
      int oi = obase + c * S_ + i;
      if (xf32) ((float*)out)[oi] = ((const float*)x)[xbase + c * P_ + p0];
      else      ((u16*)out)[oi]   = ((const u16*)x)[xbase + c * P_ + p0];
    }
  }
}

extern "C" void kernel_launch(void* const* d_in, const int* in_sizes, int n_in,
                              void* d_out, int out_size, void* d_ws, size_t ws_size,
                              hipStream_t stream) {
  const void* x     = d_in[0];
  const void* Wpos  = d_in[1];
  const void* bpos  = d_in[2];
  const void* g2    = d_in[3];
  const void* be2   = d_in[4];
  const void* Wconv = d_in[5];
  const void* bconv = d_in[6];
  const void* g1    = d_in[7];
  const void* be1   = d_in[8];
  const void* Wa1   = d_in[9];
  const void* ba1   = d_in[10];
  const void* Wa2   = d_in[11];
  const void* ba2   = d_in[12];
  const void* Wb1   = d_in[13];
  const void* bb1   = d_in[14];
  const void* Wb2   = d_in[15];
  const void* bb2   = d_in[16];
  (void)d_ws; (void)ws_size; (void)in_sizes; (void)n_in;

  hipLaunchKernelGGL(k_prep,    dim3(2),    dim3(1024), 0, stream, x);
  hipLaunchKernelGGL(k_hist,    dim3(32),   dim3(256),  0, stream, x);
  hipLaunchKernelGGL(k_scan_dt, dim3(2),    dim3(256),  0, stream);
  hipLaunchKernelGGL(k_scatter, dim3(32),   dim3(256),  0, stream, x);
  hipLaunchKernelGGL(k_knn2,    dim3(2048), dim3(256),  0, stream, x);
  hipLaunchKernelGGL(k_tail,    dim3(256),  dim3(256),  0, stream, x,
                     Wpos, bpos, Wconv, bconv);
  hipLaunchKernelGGL(k_pass2,   dim3(256),  dim3(256),  0, stream, x,
                     Wpos, bpos, Wconv, bconv, g1, be1, g2, be2,
                     Wa1, ba1, Wa2, ba2, Wb1, bb1, Wb2, bb2, d_out);
}